// Round 9
// baseline (415.503 us; speedup 1.0000x reference)
//
#include <hip/hip_runtime.h>

#define B_ 32
#define N_ 1009
#define C_ 768
#define H_ 12
#define D_ 64
#define M_ (B_*N_)          // 32288 tokens
#define MT_ 253             // ceil(M/128)
#define MPAD_ (MT_*128)     // 32384
#define NKV_ 1024           // padded sequence length for q/k/v storage

typedef __attribute__((ext_vector_type(4))) float f32x4;
typedef __attribute__((ext_vector_type(16))) float f32x16;
typedef __attribute__((ext_vector_type(8))) short s16x8;

__device__ __forceinline__ unsigned short f2bf(float f) {
  union { float f; unsigned u; } x; x.f = f;
  unsigned r = x.u + 0x7fffu + ((x.u >> 16) & 1u);
  return (unsigned short)(r >> 16);
}

__device__ __forceinline__ f32x4 mfma16(s16x8 a, s16x8 b, f32x4 c) {
  return __builtin_amdgcn_mfma_f32_16x16x32_bf16(a, b, c, 0, 0, 0);
}

__device__ __forceinline__ f32x16 mfma32(s16x8 a, s16x8 b, f32x16 c) {
  return __builtin_amdgcn_mfma_f32_32x32x16_bf16(a, b, c, 0, 0, 0);
}

__device__ __forceinline__ void async16(const void* g, void* l) {
  __builtin_amdgcn_global_load_lds((const __attribute__((address_space(1))) void*)g,
                                   (__attribute__((address_space(3))) void*)l, 16, 0, 0);
}

__device__ __forceinline__ float exp2_fast(float x) {  // 2^x via v_exp_f32
  float r; asm("v_exp_f32 %0, %1" : "=v"(r) : "v"(x)); return r;
}

__device__ __forceinline__ unsigned cvt_pk_bf16(float lo, float hi) {
  unsigned r; asm("v_cvt_pk_bf16_f32 %0, %1, %2" : "=v"(r) : "v"(lo), "v"(hi)); return r;
}

// bijective XCD-chunk swizzle (m204): XCD x gets a contiguous range of work ids
template<int NWG>
__device__ __forceinline__ int xcd_swz(int bid) {
  constexpr int q = NWG >> 3, r = NWG & 7;
  const int x = bid & 7, l = bid >> 3;
  return (x < r ? x * (q + 1) : r * (q + 1) + (x - r) * q) + l;
}

// ---------------- x fp32 -> bf16 (pad rows zeroed) ----------------
__global__ void convert_x(const float* __restrict__ x, unsigned short* __restrict__ xb) {
  const long e = ((long)blockIdx.x * 256 + threadIdx.x) * 8;
  const long row = e / 768;
  s16x8 v;
  if (row < M_) {
#pragma unroll
    for (int j = 0; j < 8; ++j) v[j] = (short)f2bf(x[e + j]);
  } else {
    v = (s16x8){0,0,0,0,0,0,0,0};
  }
  *(s16x8*)&xb[e] = v;
}

// ---------------- W [R][C] fp32 -> W^T [C][R] bf16 ----------------
__global__ void transpose_convert(const float* __restrict__ in, unsigned short* __restrict__ out,
                                  int R, int Ccols) {
  __shared__ float tile[64][65];
  const int tc = blockIdx.x * 64, tr = blockIdx.y * 64;
#pragma unroll
  for (int i = 0; i < 16; ++i) {
    const int e = i * 256 + threadIdx.x;
    const int r = e >> 6, c = e & 63;
    tile[r][c] = in[(long)(tr + r) * Ccols + tc + c];
  }
  __syncthreads();
#pragma unroll
  for (int i = 0; i < 16; ++i) {
    const int e = i * 256 + threadIdx.x;
    const int c = e >> 6, r = e & 63;
    out[(long)(tc + c) * R + tr + r] = f2bf(tile[r][c]);
  }
}

// ---------------- zero the padding tokens 1009..1023 of K and V^T ----------------
__global__ void zero_pad(unsigned short* __restrict__ kb, unsigned short* __restrict__ vt) {
  const int t = blockIdx.x * 256 + threadIdx.x;
  if (t >= 368640) return;                       // 384*15*64 == 24576*15
  const int d = t & 63;
  const int r = t >> 6;                          // [0,5760)
  const int bh = r / 15, tok = 1009 + (r - bh * 15);
  kb[(((long)bh << 10) + tok) * 64 + d] = 0;     // K: [BH][1024][64]
  const int c = t % 15, row = t / 15;            // row < 24576
  vt[((long)row << 10) + 1009 + c] = 0;          // V^T: [BH*64 rows][1024]
}

// ---------------- GEMM: A[M x 768] bf16 row-major, Bt[N x 768] bf16 (B^T) ----------------
// 32x32x16 MFMA (2382 TF pipe vs 2075 for 16x16, half the issue slots). Wave tile 64x64 =
// 2x2 blocks of 32x32, acc f32x16 each. Frag: row=lane&31, k=(lane>>5)*8+j; C-layout:
// col=lane&31, row=(r&3)+8*(r>>2)+4*(lane>>5). LDS chunk swizzle extended to
// ((row>>1)^(row>>3))&3 so 32-row frag reads stay at the 8-lane/bank-quad minimum.
// Grid: A-reuse-major + bijective XCD chunking; dbuf + counted vmcnt(4) K-loop (r6).
// MODE 0 epilogues through LDS (q/k coalesced 16B; V transposed). MODE 1: fp32 + bias.
template<int MODE>
__global__ __launch_bounds__(256, 4)
void gemm_bt(const unsigned short* __restrict__ A,
             const unsigned short* __restrict__ Bt,
             const float* __restrict__ bias,
             unsigned short* __restrict__ qo,
             unsigned short* __restrict__ ko,
             unsigned short* __restrict__ vo,
             float* __restrict__ fo) {
  // layout (bytes): As[0] @0, As[1] @8192, Bs[0] @16384, Bs[1] @24576; epilogue tile reuses all
  __shared__ __align__(16) unsigned short smem[17408];   // 34816 B -> 4 blocks/CU
  const int tid = threadIdx.x;
  const int lane = tid & 63;
  const int wv = tid >> 6;
  constexpr int NBN = (MODE == 0) ? 18 : 6;
  const int swzid = xcd_swz<MT_ * NBN>(blockIdx.x);
  const int bm = swzid / NBN;
  const int bn = swzid - bm * NBN;
  const int row0 = bm * 128;
  const int col0 = bn * 128;
  const int wr = (wv >> 1) * 64;
  const int wc = (wv & 1) * 64;
  const int l31 = lane & 31, hi = lane >> 5;

  // stage one 128x32 K-step of A and B into buffer bufsel (4 async16/thread)
  auto stage = [&](int bufsel, int kt) {
#pragma unroll
    for (int c = 0; c < 2; ++c) {
      const int lds_off = c * 4096 + wv * 1024;    // wave-uniform byte base within tile
      const int gg = c * 256 + wv * 64 + lane;     // this lane's 16B granule
      const int row = gg >> 2;                     // tile row (4 granules/row)
      const int ck = ((gg & 3) ^ (((row >> 1) ^ (row >> 3)) & 3)) << 3;  // pre-swizzled chunk
      async16(A + (long)(row0 + row) * 768 + kt + ck, (char*)smem + bufsel * 8192 + lds_off);
      async16(Bt + (long)(col0 + row) * 768 + kt + ck, (char*)smem + 16384 + bufsel * 8192 + lds_off);
    }
  };

  f32x16 acc[2][2] = {};
  stage(0, 0);
  for (int it = 0; it < 24; ++it) {
    const int buf = it & 1;
    if (it + 1 < 24) {
      stage(buf ^ 1, (it + 1) * 32);
      asm volatile("s_waitcnt vmcnt(4)" ::: "memory");   // current tile's 4 DMAs landed
    } else {
      asm volatile("s_waitcnt vmcnt(0)" ::: "memory");
    }
    __builtin_amdgcn_s_barrier();

    const unsigned short* Asb = smem + buf * 4096;          // shorts
    const unsigned short* Bsb = smem + 8192 + buf * 4096;
    s16x8 af[2][2], bfr[2][2];
#pragma unroll
    for (int b2 = 0; b2 < 2; ++b2) {
      const int rA = wr + b2 * 32 + l31;
      const int swA = ((rA >> 1) ^ (rA >> 3)) & 3;
      const int rB = wc + b2 * 32 + l31;
      const int swB = ((rB >> 1) ^ (rB >> 3)) & 3;
#pragma unroll
      for (int kin = 0; kin < 2; ++kin) {
        af[b2][kin]  = *(const s16x8*)&Asb[rA * 32 + (((kin * 2 + hi) ^ swA) << 3)];
        bfr[b2][kin] = *(const s16x8*)&Bsb[rB * 32 + (((kin * 2 + hi) ^ swB) << 3)];
      }
    }
    __builtin_amdgcn_s_setprio(1);
#pragma unroll
    for (int kin = 0; kin < 2; ++kin)
#pragma unroll
      for (int m2 = 0; m2 < 2; ++m2)
#pragma unroll
        for (int n2 = 0; n2 < 2; ++n2)
          acc[m2][n2] = mfma32(af[m2][kin], bfr[n2][kin], acc[m2][n2]);
    __builtin_amdgcn_s_setprio(0);

    // drain our ds_reads before anyone overwrites this buffer next iteration
    asm volatile("s_waitcnt lgkmcnt(0)" ::: "memory");
    __builtin_amdgcn_s_barrier();
  }

  if (MODE == 0 && col0 < 1536) {
    // ---- q/k path: stage [tok 0..127][col 0..127] bf16 in LDS, then 16B stores ----
    const int qsel = col0 < 768;                 // whole block is q or k (col0 mult of 128)
#pragma unroll
    for (int m2 = 0; m2 < 2; ++m2)
#pragma unroll
      for (int n2 = 0; n2 < 2; ++n2)
#pragma unroll
        for (int r = 0; r < 16; ++r) {
          const int tk = wr + m2 * 32 + (r & 3) + ((r >> 2) << 3) + (hi << 2);
          const int cl = wc + n2 * 32 + l31;
          float val = acc[m2][n2][r] + bias[col0 + cl];
          if (qsel) val *= 0.18033688011112042f;  // 0.125 * log2(e): exp2-domain scores
          smem[tk * 136 + cl] = f2bf(val);
        }
    __syncthreads();
    unsigned short* const dst = qsel ? qo : ko;
    const int colb = col0 - (qsel ? 0 : 768);
#pragma unroll
    for (int it = 0; it < 8; ++it) {
      const int g = it * 256 + tid;
      const int tk = g >> 4;                     // local token
      const int ch = (g & 15) * 8;               // col chunk (8 shorts = 16B)
      const int grow = row0 + tk;
      if (grow < M_) {
        const s16x8 vv = *(const s16x8*)&smem[tk * 136 + ch];   // 16B aligned (272B rows)
        const int b = grow / N_;
        const int ntok = grow - b * N_;
        const int rem = colb + ch;
        const int h = rem >> 6, d = rem & 63;    // d multiple of 8 -> dest 16B aligned
        *(s16x8*)&dst[(((((long)b * H_ + h) << 10) + ntok) << 6) + d] = vv;
      }
    }
    return;
  }

  if (MODE == 0) {
    // ---- V path: stage transposed tile [d_local 0..127][tok 0..127] in LDS ----
#pragma unroll
    for (int m2 = 0; m2 < 2; ++m2)
#pragma unroll
      for (int n2 = 0; n2 < 2; ++n2)
#pragma unroll
        for (int r = 0; r < 16; ++r) {
          const int dl = wc + n2 * 32 + l31;
          const int tk = wr + m2 * 32 + (r & 3) + ((r >> 2) << 3) + (hi << 2);
          smem[dl * 136 + tk] = f2bf(acc[m2][n2][r] + bias[col0 + dl]);
        }
    __syncthreads();
    const int h0 = (col0 - 1536) >> 6;
    const int b0 = row0 / N_;
    const int split = (b0 + 1) * N_ - row0;   // block tokens [0,split) belong to batch b0
#pragma unroll
    for (int it = 0; it < 8; ++it) {
      const int g = it * 256 + tid;
      const int dl = g >> 4;
      const int t8 = (g & 15) * 8;
      const s16x8 vv = *(const s16x8*)&smem[dl * 136 + t8];   // 16B aligned
      const int hh = h0 + (dl >> 6), dd = dl & 63;
#pragma unroll
      for (int jj = 0; jj < 8; ++jj) {
        const int tkb = t8 + jj;
        const int grow = row0 + tkb;
        if (grow < M_) {
          const int bb = (tkb < split) ? b0 : b0 + 1;
          const int ntok = grow - bb * N_;
          vo[(((((long)bb * H_ + hh) << 6) + dd) << 10) + ntok] = (unsigned short)vv[jj];
        }
      }
    }
    return;
  }

  // ---- MODE 1: fp32 out + bias (32 lanes x 4B = 128B coalesced rows) ----
#pragma unroll
  for (int m2 = 0; m2 < 2; ++m2) {
#pragma unroll
    for (int r = 0; r < 16; ++r) {
      const int grow = row0 + wr + m2 * 32 + (r & 3) + ((r >> 2) << 3) + (hi << 2);
      if (grow < M_) {
#pragma unroll
        for (int n2 = 0; n2 < 2; ++n2) {
          const int col = col0 + wc + n2 * 32 + l31;
          fo[(long)grow * 768 + col] = acc[m2][n2][r] + bias[col];
        }
      }
    }
  }
}

// ---------------- prompt segment: out[n=0] = v[n=0] (V^T layout) ----------------
__global__ void misc_copy(const unsigned short* __restrict__ vt, unsigned short* __restrict__ og) {
  const int t = blockIdx.x * 256 + threadIdx.x;
  if (t >= B_ * H_ * D_) return;
  const int d = t & 63;
  const int bh = t >> 6;
  const int b = bh / H_, h = bh - b * H_;
  og[((long)b * N_) * 768 + h * 64 + d] = vt[(((long)bh << 6) + d) << 10];
}

// ---------------- flash attention: block = (b, h, 64-query tile), KVBLK=64 ----------------
// SWAPPED layout: QK^T computed as mfma(K,Q) -> S^T[key][q=lane&15]; PV as mfma(V^T,P)
// -> O^T[d][q=lane&15]. Softmax state (m,l) is one scalar per lane. Defer-max (T13,
// THR=8 log2-domain, P <= 256): skip corr+rescale when tile max is within 8 of running max.
__global__ __launch_bounds__(256, 4)
void attn_kernel(const unsigned short* __restrict__ qg,
                 const unsigned short* __restrict__ kg,
                 const unsigned short* __restrict__ vtg,
                 unsigned short* __restrict__ og) {
  __shared__ __align__(16) unsigned short Ks[2][64 * 64];
  __shared__ __align__(16) unsigned short Vts[2][64 * 64];
  __shared__ __align__(16) unsigned short Ps[64 * 64];

  const int bid = blockIdx.x;
  const int swz = (bid & 7) * 768 + (bid >> 3);
  const int tile = swz & 15;
  const int bh = swz >> 4;
  const int b = bh / H_;
  const int h = bh - b * H_;
  int qbase, qend, kstart, ktiles, kend;
  if (tile < 7) { qbase = 1 + 64 * tile;       qend = 433;  kstart = 1; ktiles = 7;  kend = 433; }
  else          { qbase = 433 + 64 * (tile-7); qend = 1009; kstart = 0; ktiles = 16; kend = 1009; }
  const long base  = (long)bh << 10;
  const long vbase = (long)bh << 6;
  const int tid = threadIdx.x, lane = tid & 63, wv = tid >> 6;
  const int q15 = lane & 15, q7 = lane & 7, g = lane >> 4;

  s16x8 qa[2];
  {
    const unsigned short* qp = qg + (base + qbase + wv * 16 + q15) * 64;
    qa[0] = *(const s16x8*)(qp + g * 8);
    qa[1] = *(const s16x8*)(qp + 32 + g * 8);
  }
  asm volatile("s_waitcnt vmcnt(0)" ::: "memory");

  f32x4 o[4] = {};
  float mrow = -1e30f, lrow = 0.f;

  auto stage = [&](int bufsel, int kb0) {
#pragma unroll
    for (int it = 0; it < 2; ++it) {
      const int ldsoff = (it * 256 + wv * 64) * 16;
      const int gr = it * 256 + wv * 64 + lane;
      const int rl = gr >> 3;
      const int cs = (gr & 7) ^ (rl & 7);
      async16(kg + ((base + kb0 + rl) << 6) + cs * 8, (char*)&Ks[bufsel][0] + ldsoff);
      async16(vtg + ((vbase + rl) << 10) + kb0 + cs * 8, (char*)&Vts[bufsel][0] + ldsoff);
    }
  };

  const int prow = wv * 16 + q15;

  stage(0, kstart);
  for (int kt = 0; kt < ktiles; ++kt) {
    const int buf = kt & 1;
    const int kbase0 = kstart + 64 * kt;
    if (kt + 1 < ktiles) {
      stage(buf ^ 1, kbase0 + 64);
      asm volatile("s_waitcnt vmcnt(4)" ::: "memory");
    } else {
      asm volatile("s_waitcnt vmcnt(0)" ::: "memory");
    }
    __builtin_amdgcn_s_barrier();

    f32x4 s4[4];
    __builtin_amdgcn_s_setprio(1);
#pragma unroll
    for (int n = 0; n < 4; ++n) {
      const int krow = n * 16 + q15;
      const int r7 = krow & 7;
      f32x4 a = {};
      a = mfma16(*(const s16x8*)&Ks[buf][krow * 64 + ((g ^ r7) << 3)],       qa[0], a);
      a = mfma16(*(const s16x8*)&Ks[buf][krow * 64 + (((4 + g) ^ r7) << 3)], qa[1], a);
      s4[n] = a;
    }
    __builtin_amdgcn_s_setprio(0);

    if (kbase0 + 64 > kend) {
#pragma unroll
      for (int n = 0; n < 4; ++n)
#pragma unroll
        for (int j = 0; j < 4; ++j)
          if (kbase0 + n * 16 + g * 4 + j >= kend) s4[n][j] = -1e30f;
    }

    float rmax = fmaxf(
        fmaxf(fmaxf(fmaxf(s4[0][0], s4[0][1]), fmaxf(s4[0][2], s4[0][3])),
              fmaxf(fmaxf(s4[1][0], s4[1][1]), fmaxf(s4[1][2], s4[1][3]))),
        fmaxf(fmaxf(fmaxf(s4[2][0], s4[2][1]), fmaxf(s4[2][2], s4[2][3])),
              fmaxf(fmaxf(s4[3][0], s4[3][1]), fmaxf(s4[3][2], s4[3][3]))));
    rmax = fmaxf(rmax, __shfl_xor(rmax, 16));
    rmax = fmaxf(rmax, __shfl_xor(rmax, 32));

    // defer-max: keep old m when tile max within THR=8 (log2 units; P bounded by 2^8)
    if (!__all(rmax <= mrow + 8.f)) {
      const float mnew = fmaxf(mrow, rmax);
      const float corr = exp2_fast(mrow - mnew);
      mrow = mnew;
      lrow *= corr;
#pragma unroll
      for (int f = 0; f < 4; ++f)
#pragma unroll
        for (int j = 0; j < 4; ++j) o[f][j] *= corr;
    }
    const float mnew = mrow;

    float psum = 0.f;
#pragma unroll
    for (int n = 0; n < 4; ++n) {
#pragma unroll
      for (int j = 0; j < 4; ++j) {
        s4[n][j] = exp2_fast(s4[n][j] - mnew);
        psum += s4[n][j];
      }
      uint2 pw;
      pw.x = cvt_pk_bf16(s4[n][0], s4[n][1]);
      pw.y = cvt_pk_bf16(s4[n][2], s4[n][3]);
      *(uint2*)((char*)Ps + prow * 128 + (((n * 2 + (g >> 1)) ^ q7) << 4) + (g & 1) * 8) = pw;
    }
    psum += __shfl_xor(psum, 16);
    psum += __shfl_xor(psum, 32);
    lrow += psum;

    s16x8 pa[2];
#pragma unroll
    for (int kf = 0; kf < 2; ++kf)
      pa[kf] = *(const s16x8*)((char*)Ps + prow * 128 + (((kf * 4 + g) ^ q7) << 4));
    __builtin_amdgcn_s_setprio(1);
#pragma unroll
    for (int f = 0; f < 4; ++f) {
      const int vrow = f * 16 + q15;
      const int v7 = vrow & 7;
#pragma unroll
      for (int kf = 0; kf < 2; ++kf) {
        const s16x8 vb = *(const s16x8*)&Vts[buf][vrow * 64 + (((kf * 4 + g) ^ v7) << 3)];
        o[f] = mfma16(vb, pa[kf], o[f]);
      }
    }
    __builtin_amdgcn_s_setprio(0);

    asm volatile("s_waitcnt lgkmcnt(0)" ::: "memory");
    __builtin_amdgcn_s_barrier();
  }

  const int qrow = qbase + wv * 16 + q15;
  if (qrow < qend) {
    const float inv = 1.0f / lrow;
    unsigned short* op = og + ((long)b * N_ + qrow) * 768 + h * 64 + g * 4;
#pragma unroll
    for (int f = 0; f < 4; ++f) {
      uint2 ow;
      ow.x = cvt_pk_bf16(o[f][0] * inv, o[f][1] * inv);
      ow.y = cvt_pk_bf16(o[f][2] * inv, o[f][3] * inv);
      *(uint2*)(op + f * 16) = ow;
    }
  }
}

extern "C" void kernel_launch(void* const* d_in, const int* in_sizes, int n_in,
                              void* d_out, int out_size, void* d_ws, size_t ws_size,
                              hipStream_t stream) {
  const float* x      = (const float*)d_in[0];
  const float* W_qkv  = (const float*)d_in[1];
  const float* b_qkv  = (const float*)d_in[2];
  const float* W_proj = (const float*)d_in[3];
  const float* b_proj = (const float*)d_in[4];
  float* out = (float*)d_out;

  unsigned short* ws = (unsigned short*)d_ws;
  unsigned short* wqkvT  = ws;                                  // [2304][768] bf16
  unsigned short* wprojT = wqkvT + (long)2304 * 768;            // [768][768] bf16
  unsigned short* qb = wprojT + (long)768 * 768;                // [B][H][1024][64] bf16
  const long kvsz = (long)B_ * H_ * NKV_ * D_;
  unsigned short* kb = qb + kvsz;                               // [B][H][1024][64] bf16
  unsigned short* vb = kb + kvsz;                               // V^T: [B][H][64][1024] bf16
  unsigned short* xb = vb + kvsz;                               // [MPAD][768] bf16
  unsigned short* attnout = xb;  // aliased: xb dead after QKV GEMM (stream-ordered)

  zero_pad<<<1440, 256, 0, stream>>>(kb, vb);
  convert_x<<<12144, 256, 0, stream>>>(x, xb);
  transpose_convert<<<dim3(2304 / 64, 768 / 64), 256, 0, stream>>>(W_qkv, wqkvT, 768, 2304);
  transpose_convert<<<dim3(768 / 64, 768 / 64), 256, 0, stream>>>(W_proj, wprojT, 768, 768);
  gemm_bt<0><<<MT_ * 18, 256, 0, stream>>>(xb, wqkvT, b_qkv, qb, kb, vb, nullptr);
  misc_copy<<<96, 256, 0, stream>>>(vb, attnout);
  attn_kernel<<<B_ * H_ * 16, 256, 0, stream>>>(qb, kb, vb, attnout);
  gemm_bt<1><<<MT_ * 6, 256, 0, stream>>>(attnout, wprojT, b_proj, nullptr, nullptr, nullptr, out);
}

// Round 10
// 403.449 us; speedup vs baseline: 1.0299x; 1.0299x over previous
//
#include <hip/hip_runtime.h>

#define B_ 32
#define N_ 1009
#define C_ 768
#define H_ 12
#define D_ 64
#define M_ (B_*N_)          // 32288 tokens
#define MT_ 253             // ceil(M/128)
#define MPAD_ (MT_*128)     // 32384
#define NKV_ 1024           // padded sequence length for q/k/v storage

typedef __attribute__((ext_vector_type(4))) float f32x4;
typedef __attribute__((ext_vector_type(8))) short s16x8;

__device__ __forceinline__ unsigned short f2bf(float f) {
  union { float f; unsigned u; } x; x.f = f;
  unsigned r = x.u + 0x7fffu + ((x.u >> 16) & 1u);
  return (unsigned short)(r >> 16);
}

__device__ __forceinline__ f32x4 mfma16(s16x8 a, s16x8 b, f32x4 c) {
  return __builtin_amdgcn_mfma_f32_16x16x32_bf16(a, b, c, 0, 0, 0);
}

__device__ __forceinline__ void async16(const void* g, void* l) {
  __builtin_amdgcn_global_load_lds((const __attribute__((address_space(1))) void*)g,
                                   (__attribute__((address_space(3))) void*)l, 16, 0, 0);
}

__device__ __forceinline__ float exp2_fast(float x) {  // 2^x via v_exp_f32
  float r; asm("v_exp_f32 %0, %1" : "=v"(r) : "v"(x)); return r;
}

__device__ __forceinline__ unsigned cvt_pk_bf16(float lo, float hi) {
  unsigned r; asm("v_cvt_pk_bf16_f32 %0, %1, %2" : "=v"(r) : "v"(lo), "v"(hi)); return r;
}

// bijective XCD-chunk swizzle (m204): XCD x gets a contiguous range of work ids
template<int NWG>
__device__ __forceinline__ int xcd_swz(int bid) {
  constexpr int q = NWG >> 3, r = NWG & 7;
  const int x = bid & 7, l = bid >> 3;
  return (x < r ? x * (q + 1) : r * (q + 1) + (x - r) * q) + l;
}

// ---------------- x fp32 -> bf16 (pad rows zeroed) ----------------
__global__ void convert_x(const float* __restrict__ x, unsigned short* __restrict__ xb) {
  const long e = ((long)blockIdx.x * 256 + threadIdx.x) * 8;
  const long row = e / 768;
  s16x8 v;
  if (row < M_) {
#pragma unroll
    for (int j = 0; j < 8; ++j) v[j] = (short)f2bf(x[e + j]);
  } else {
    v = (s16x8){0,0,0,0,0,0,0,0};
  }
  *(s16x8*)&xb[e] = v;
}

// ---------------- W [R][C] fp32 -> W^T [C][R] bf16 ----------------
__global__ void transpose_convert(const float* __restrict__ in, unsigned short* __restrict__ out,
                                  int R, int Ccols) {
  __shared__ float tile[64][65];
  const int tc = blockIdx.x * 64, tr = blockIdx.y * 64;
#pragma unroll
  for (int i = 0; i < 16; ++i) {
    const int e = i * 256 + threadIdx.x;
    const int r = e >> 6, c = e & 63;
    tile[r][c] = in[(long)(tr + r) * Ccols + tc + c];
  }
  __syncthreads();
#pragma unroll
  for (int i = 0; i < 16; ++i) {
    const int e = i * 256 + threadIdx.x;
    const int c = e >> 6, r = e & 63;
    out[(long)(tc + c) * R + tr + r] = f2bf(tile[r][c]);
  }
}

// ---------------- zero the padding tokens 1009..1023 of K and V^T ----------------
__global__ void zero_pad(unsigned short* __restrict__ kb, unsigned short* __restrict__ vt) {
  const int t = blockIdx.x * 256 + threadIdx.x;
  if (t >= 368640) return;                       // 384*15*64 == 24576*15
  const int d = t & 63;
  const int r = t >> 6;                          // [0,5760)
  const int bh = r / 15, tok = 1009 + (r - bh * 15);
  kb[(((long)bh << 10) + tok) * 64 + d] = 0;     // K: [BH][1024][64]
  const int c = t % 15, row = t / 15;            // row < 24576
  vt[((long)row << 10) + 1009 + c] = 0;          // V^T: [BH*64 rows][1024]
}

// ---------------- GEMM: A[M x 768] bf16 row-major, Bt[N x 768] bf16 (B^T) ----------------
// Grid: A-reuse-major (bm = swz/NBN) + bijective XCD chunking -> XCD working set L2-fits.
// K-loop (NEW): 3-slot LDS rotation, ONE barrier per K-step. Schedule per iter t:
//   vmcnt(4) [tile t landed] -> barrier -> stage slot[(t+2)%3] [slot last read at t-1,
//   drained: every wave past barrier(t) completed its t-1 reads before its t-1 MFMAs]
//   -> ds_read slot[t%3] -> MFMA. Prefetch depth 2 tiles (vs 1), 24 barriers (vs 48).
// LDS tiles XOR-swizzled (chunk ^= (row>>1)&3, pre-swizzled global src) -> 2-way-free reads.
// MODE 0 epilogues through LDS (q/k coalesced 16B, q pre-scaled 0.125*log2e; V transposed).
// MODE 1: fp32 out + bias, direct.
template<int MODE>
__global__ __launch_bounds__(256, 3)
void gemm_bt(const unsigned short* __restrict__ A,
             const unsigned short* __restrict__ Bt,
             const float* __restrict__ bias,
             unsigned short* __restrict__ qo,
             unsigned short* __restrict__ ko,
             unsigned short* __restrict__ vo,
             float* __restrict__ fo) {
  // layout (bytes): slot s @ s*16384 (A 8KB | B 8KB), s=0..2; epilogue tile reuses slot 0/1
  __shared__ __align__(16) unsigned short smem[24576];   // 49152 B -> 3 blocks/CU
  const int tid = threadIdx.x;
  const int lane = tid & 63;
  const int wv = tid >> 6;
  constexpr int NBN = (MODE == 0) ? 18 : 6;
  const int swzid = xcd_swz<MT_ * NBN>(blockIdx.x);
  const int bm = swzid / NBN;
  const int bn = swzid - bm * NBN;
  const int row0 = bm * 128;
  const int col0 = bn * 128;
  const int wr = (wv >> 1) * 64;
  const int wc = (wv & 1) * 64;

  // stage one 128x32 K-step of A and B into slot (4 async16/thread)
  auto stage = [&](int slot, int kt) {
#pragma unroll
    for (int c = 0; c < 2; ++c) {
      const int lds_off = c * 4096 + wv * 1024;    // wave-uniform byte base within half
      const int gg = c * 256 + wv * 64 + lane;     // this lane's 16B granule
      const int row = gg >> 2;                     // tile row (4 granules/row)
      const int ck = ((gg & 3) ^ ((row >> 1) & 3)) << 3;  // pre-swizzled source chunk
      async16(A + (long)(row0 + row) * 768 + kt + ck, (char*)smem + slot * 16384 + lds_off);
      async16(Bt + (long)(col0 + row) * 768 + kt + ck, (char*)smem + slot * 16384 + 8192 + lds_off);
    }
  };

  f32x4 acc[4][4] = {};
  stage(0, 0);       // tile 0
  stage(1, 32);      // tile 1
  for (int it = 0; it < 24; ++it) {
    const int sl = it % 3;
    if (it + 1 < 24) {
      asm volatile("s_waitcnt vmcnt(4)" ::: "memory");   // tile it landed; it+1 may fly
    } else {
      asm volatile("s_waitcnt vmcnt(0)" ::: "memory");
    }
    __builtin_amdgcn_s_barrier();
    if (it + 2 < 24) stage((it + 2) % 3, (it + 2) * 32); // overwrite slot read at it-1 (drained)

    const unsigned short* Asb = smem + sl * 8192;           // shorts
    const unsigned short* Bsb = Asb + 4096;
    s16x8 af[4], bfr[4];
#pragma unroll
    for (int m = 0; m < 4; ++m) {
      const int rA = wr + m * 16 + (lane & 15);
      af[m] = *(const s16x8*)&Asb[rA * 32 + (((lane >> 4) ^ ((rA >> 1) & 3)) << 3)];
    }
#pragma unroll
    for (int n = 0; n < 4; ++n) {
      const int rB = wc + n * 16 + (lane & 15);
      bfr[n] = *(const s16x8*)&Bsb[rB * 32 + (((lane >> 4) ^ ((rB >> 1) & 3)) << 3)];
    }
    __builtin_amdgcn_s_setprio(1);
#pragma unroll
    for (int m = 0; m < 4; ++m)
#pragma unroll
      for (int n = 0; n < 4; ++n)
        acc[m][n] = mfma16(af[m], bfr[n], acc[m][n]);
    __builtin_amdgcn_s_setprio(0);
  }
  __syncthreads();   // all waves done with K-loop before epilogue reuses smem

  if (MODE == 0 && col0 < 1536) {
    // ---- q/k path: stage [tok 0..127][col 0..127] bf16 in LDS, then 16B stores ----
    const int qsel = col0 < 768;                 // whole block is q or k (col0 mult of 128)
#pragma unroll
    for (int m = 0; m < 4; ++m)
#pragma unroll
      for (int j = 0; j < 4; ++j)
#pragma unroll
        for (int n = 0; n < 4; ++n) {
          const int tk = wr + m * 16 + (lane >> 4) * 4 + j;
          const int cl = wc + n * 16 + (lane & 15);
          float val = acc[m][n][j] + bias[col0 + cl];
          if (qsel) val *= 0.18033688011112042f;  // 0.125 * log2(e): exp2-domain scores
          smem[tk * 136 + cl] = f2bf(val);
        }
    __syncthreads();
    unsigned short* const dst = qsel ? qo : ko;
    const int colb = col0 - (qsel ? 0 : 768);
#pragma unroll
    for (int it = 0; it < 8; ++it) {
      const int g = it * 256 + tid;
      const int tk = g >> 4;                     // local token
      const int ch = (g & 15) * 8;               // col chunk (8 shorts = 16B)
      const int grow = row0 + tk;
      if (grow < M_) {
        const s16x8 vv = *(const s16x8*)&smem[tk * 136 + ch];   // 16B aligned (272B rows)
        const int b = grow / N_;
        const int ntok = grow - b * N_;
        const int rem = colb + ch;
        const int h = rem >> 6, d = rem & 63;    // d multiple of 8 -> dest 16B aligned
        *(s16x8*)&dst[(((((long)b * H_ + h) << 10) + ntok) << 6) + d] = vv;
      }
    }
    return;
  }

  if (MODE == 0) {
    // ---- V path: stage transposed tile [d_local 0..127][tok 0..127] in LDS ----
#pragma unroll
    for (int m = 0; m < 4; ++m)
#pragma unroll
      for (int j = 0; j < 4; ++j)
#pragma unroll
        for (int n = 0; n < 4; ++n) {
          const int dl = wc + n * 16 + (lane & 15);
          const int tk = wr + m * 16 + (lane >> 4) * 4 + j;
          smem[dl * 136 + tk] = f2bf(acc[m][n][j] + bias[col0 + dl]);
        }
    __syncthreads();
    const int h0 = (col0 - 1536) >> 6;
    const int b0 = row0 / N_;
    const int split = (b0 + 1) * N_ - row0;   // block tokens [0,split) belong to batch b0
#pragma unroll
    for (int it = 0; it < 8; ++it) {
      const int g = it * 256 + tid;
      const int dl = g >> 4;
      const int t8 = (g & 15) * 8;
      const s16x8 vv = *(const s16x8*)&smem[dl * 136 + t8];   // 16B aligned
      const int hh = h0 + (dl >> 6), dd = dl & 63;
#pragma unroll
      for (int jj = 0; jj < 8; ++jj) {
        const int tkb = t8 + jj;
        const int grow = row0 + tkb;
        if (grow < M_) {
          const int bb = (tkb < split) ? b0 : b0 + 1;
          const int ntok = grow - bb * N_;
          vo[(((((long)bb * H_ + hh) << 6) + dd) << 10) + ntok] = (unsigned short)vv[jj];
        }
      }
    }
    return;
  }

  // ---- MODE 1: fp32 out + bias ----
#pragma unroll
  for (int m = 0; m < 4; ++m) {
#pragma unroll
    for (int j = 0; j < 4; ++j) {
      const int grow = row0 + wr + m * 16 + (lane >> 4) * 4 + j;
      if (grow < M_) {
#pragma unroll
        for (int n = 0; n < 4; ++n) {
          const int col = col0 + wc + n * 16 + (lane & 15);
          fo[(long)grow * 768 + col] = acc[m][n][j] + bias[col];
        }
      }
    }
  }
}

// ---------------- prompt segment: out[n=0] = v[n=0] (V^T layout) ----------------
__global__ void misc_copy(const unsigned short* __restrict__ vt, unsigned short* __restrict__ og) {
  const int t = blockIdx.x * 256 + threadIdx.x;
  if (t >= B_ * H_ * D_) return;
  const int d = t & 63;
  const int bh = t >> 6;
  const int b = bh / H_, h = bh - b * H_;
  og[((long)b * N_) * 768 + h * 64 + d] = vt[(((long)bh << 6) + d) << 10];
}

// ---------------- flash attention: block = (b, h, 64-query tile), KVBLK=64 ----------------
// SWAPPED layout: QK^T computed as mfma(K,Q) -> S^T[key][q=lane&15]; PV as mfma(V^T,P)
// -> O^T[d][q=lane&15]. Softmax state (m,l) is one scalar per lane; reductions are
// in-lane over 16 regs + 2 shfl_xor(16,32). Q pre-scaled by 0.125*log2e -> exp2 domain.
__global__ __launch_bounds__(256, 4)
void attn_kernel(const unsigned short* __restrict__ qg,
                 const unsigned short* __restrict__ kg,
                 const unsigned short* __restrict__ vtg,
                 unsigned short* __restrict__ og) {
  __shared__ __align__(16) unsigned short Ks[2][64 * 64];
  __shared__ __align__(16) unsigned short Vts[2][64 * 64];
  __shared__ __align__(16) unsigned short Ps[64 * 64];

  const int bid = blockIdx.x;
  const int swz = (bid & 7) * 768 + (bid >> 3);
  const int tile = swz & 15;
  const int bh = swz >> 4;
  const int b = bh / H_;
  const int h = bh - b * H_;
  int qbase, qend, kstart, ktiles, kend;
  if (tile < 7) { qbase = 1 + 64 * tile;       qend = 433;  kstart = 1; ktiles = 7;  kend = 433; }
  else          { qbase = 433 + 64 * (tile-7); qend = 1009; kstart = 0; ktiles = 16; kend = 1009; }
  const long base  = (long)bh << 10;
  const long vbase = (long)bh << 6;
  const int tid = threadIdx.x, lane = tid & 63, wv = tid >> 6;
  const int q15 = lane & 15, q7 = lane & 7, g = lane >> 4;

  s16x8 qa[2];
  {
    const unsigned short* qp = qg + (base + qbase + wv * 16 + q15) * 64;
    qa[0] = *(const s16x8*)(qp + g * 8);
    qa[1] = *(const s16x8*)(qp + 32 + g * 8);
  }
  asm volatile("s_waitcnt vmcnt(0)" ::: "memory");

  f32x4 o[4] = {};
  float mrow = -1e30f, lrow = 0.f;

  auto stage = [&](int bufsel, int kb0) {
#pragma unroll
    for (int it = 0; it < 2; ++it) {
      const int ldsoff = (it * 256 + wv * 64) * 16;
      const int gr = it * 256 + wv * 64 + lane;
      const int rl = gr >> 3;
      const int cs = (gr & 7) ^ (rl & 7);
      async16(kg + ((base + kb0 + rl) << 6) + cs * 8, (char*)&Ks[bufsel][0] + ldsoff);
      async16(vtg + ((vbase + rl) << 10) + kb0 + cs * 8, (char*)&Vts[bufsel][0] + ldsoff);
    }
  };

  const int prow = wv * 16 + q15;

  stage(0, kstart);
  for (int kt = 0; kt < ktiles; ++kt) {
    const int buf = kt & 1;
    const int kbase0 = kstart + 64 * kt;
    if (kt + 1 < ktiles) {
      stage(buf ^ 1, kbase0 + 64);
      asm volatile("s_waitcnt vmcnt(4)" ::: "memory");
    } else {
      asm volatile("s_waitcnt vmcnt(0)" ::: "memory");
    }
    __builtin_amdgcn_s_barrier();

    f32x4 s4[4];
    __builtin_amdgcn_s_setprio(1);
#pragma unroll
    for (int n = 0; n < 4; ++n) {
      const int krow = n * 16 + q15;
      const int r7 = krow & 7;
      f32x4 a = {};
      a = mfma16(*(const s16x8*)&Ks[buf][krow * 64 + ((g ^ r7) << 3)],       qa[0], a);
      a = mfma16(*(const s16x8*)&Ks[buf][krow * 64 + (((4 + g) ^ r7) << 3)], qa[1], a);
      s4[n] = a;
    }
    __builtin_amdgcn_s_setprio(0);

    if (kbase0 + 64 > kend) {
#pragma unroll
      for (int n = 0; n < 4; ++n)
#pragma unroll
        for (int j = 0; j < 4; ++j)
          if (kbase0 + n * 16 + g * 4 + j >= kend) s4[n][j] = -1e30f;
    }

    float rmax = fmaxf(
        fmaxf(fmaxf(fmaxf(s4[0][0], s4[0][1]), fmaxf(s4[0][2], s4[0][3])),
              fmaxf(fmaxf(s4[1][0], s4[1][1]), fmaxf(s4[1][2], s4[1][3]))),
        fmaxf(fmaxf(fmaxf(s4[2][0], s4[2][1]), fmaxf(s4[2][2], s4[2][3])),
              fmaxf(fmaxf(s4[3][0], s4[3][1]), fmaxf(s4[3][2], s4[3][3]))));
    rmax = fmaxf(rmax, __shfl_xor(rmax, 16));
    rmax = fmaxf(rmax, __shfl_xor(rmax, 32));

    const float mnew = fmaxf(mrow, rmax);
    const float corr = exp2_fast(mrow - mnew);
    mrow = mnew;
#pragma unroll
    for (int f = 0; f < 4; ++f)
#pragma unroll
      for (int j = 0; j < 4; ++j) o[f][j] *= corr;

    float psum = 0.f;
#pragma unroll
    for (int n = 0; n < 4; ++n) {
#pragma unroll
      for (int j = 0; j < 4; ++j) {
        s4[n][j] = exp2_fast(s4[n][j] - mnew);
        psum += s4[n][j];
      }
      uint2 pw;
      pw.x = cvt_pk_bf16(s4[n][0], s4[n][1]);
      pw.y = cvt_pk_bf16(s4[n][2], s4[n][3]);
      *(uint2*)((char*)Ps + prow * 128 + (((n * 2 + (g >> 1)) ^ q7) << 4) + (g & 1) * 8) = pw;
    }
    psum += __shfl_xor(psum, 16);
    psum += __shfl_xor(psum, 32);
    lrow = lrow * corr + psum;

    s16x8 pa[2];
#pragma unroll
    for (int kf = 0; kf < 2; ++kf)
      pa[kf] = *(const s16x8*)((char*)Ps + prow * 128 + (((kf * 4 + g) ^ q7) << 4));
    __builtin_amdgcn_s_setprio(1);
#pragma unroll
    for (int f = 0; f < 4; ++f) {
      const int vrow = f * 16 + q15;
      const int v7 = vrow & 7;
#pragma unroll
      for (int kf = 0; kf < 2; ++kf) {
        const s16x8 vb = *(const s16x8*)&Vts[buf][vrow * 64 + (((kf * 4 + g) ^ v7) << 3)];
        o[f] = mfma16(vb, pa[kf], o[f]);
      }
    }
    __builtin_amdgcn_s_setprio(0);

    asm volatile("s_waitcnt lgkmcnt(0)" ::: "memory");
    __builtin_amdgcn_s_barrier();
  }

  const int qrow = qbase + wv * 16 + q15;
  if (qrow < qend) {
    const float inv = 1.0f / lrow;
    unsigned short* op = og + ((long)b * N_ + qrow) * 768 + h * 64 + g * 4;
#pragma unroll
    for (int f = 0; f < 4; ++f) {
      uint2 ow;
      ow.x = cvt_pk_bf16(o[f][0] * inv, o[f][1] * inv);
      ow.y = cvt_pk_bf16(o[f][2] * inv, o[f][3] * inv);
      *(uint2*)(op + f * 16) = ow;
    }
  }
}

extern "C" void kernel_launch(void* const* d_in, const int* in_sizes, int n_in,
                              void* d_out, int out_size, void* d_ws, size_t ws_size,
                              hipStream_t stream) {
  const float* x      = (const float*)d_in[0];
  const float* W_qkv  = (const float*)d_in[1];
  const float* b_qkv  = (const float*)d_in[2];
  const float* W_proj = (const float*)d_in[3];
  const float* b_proj = (const float*)d_in[4];
  float* out = (float*)d_out;

  unsigned short* ws = (unsigned short*)d_ws;
  unsigned short* wqkvT  = ws;                                  // [2304][768] bf16
  unsigned short* wprojT = wqkvT + (long)2304 * 768;            // [768][768] bf16
  unsigned short* qb = wprojT + (long)768 * 768;                // [B][H][1024][64] bf16
  const long kvsz = (long)B_ * H_ * NKV_ * D_;
  unsigned short* kb = qb + kvsz;                               // [B][H][1024][64] bf16
  unsigned short* vb = kb + kvsz;                               // V^T: [B][H][64][1024] bf16
  unsigned short* xb = vb + kvsz;                               // [MPAD][768] bf16
  unsigned short* attnout = xb;  // aliased: xb dead after QKV GEMM (stream-ordered)

  zero_pad<<<1440, 256, 0, stream>>>(kb, vb);
  convert_x<<<12144, 256, 0, stream>>>(x, xb);
  transpose_convert<<<dim3(2304 / 64, 768 / 64), 256, 0, stream>>>(W_qkv, wqkvT, 768, 2304);
  transpose_convert<<<dim3(768 / 64, 768 / 64), 256, 0, stream>>>(W_proj, wprojT, 768, 768);
  gemm_bt<0><<<MT_ * 18, 256, 0, stream>>>(xb, wqkvT, b_qkv, qb, kb, vb, nullptr);
  misc_copy<<<96, 256, 0, stream>>>(vb, attnout);
  attn_kernel<<<B_ * H_ * 16, 256, 0, stream>>>(qb, kb, vb, attnout);
  gemm_bt<1><<<MT_ * 6, 256, 0, stream>>>(attnout, wprojT, b_proj, nullptr, nullptr, nullptr, out);
}

// Round 11
// 396.057 us; speedup vs baseline: 1.0491x; 1.0187x over previous
//
#include <hip/hip_runtime.h>

#define B_ 32
#define N_ 1009
#define C_ 768
#define H_ 12
#define D_ 64
#define M_ (B_*N_)          // 32288 tokens
#define MT_ 253             // ceil(M/128)
#define MPAD_ (MT_*128)     // 32384
#define NKV_ 1024           // padded sequence length for q/k/v storage

typedef __attribute__((ext_vector_type(4))) float f32x4;
typedef __attribute__((ext_vector_type(8))) short s16x8;

__device__ __forceinline__ unsigned short f2bf(float f) {
  union { float f; unsigned u; } x; x.f = f;
  unsigned r = x.u + 0x7fffu + ((x.u >> 16) & 1u);
  return (unsigned short)(r >> 16);
}

__device__ __forceinline__ f32x4 mfma16(s16x8 a, s16x8 b, f32x4 c) {
  return __builtin_amdgcn_mfma_f32_16x16x32_bf16(a, b, c, 0, 0, 0);
}

__device__ __forceinline__ void async16(const void* g, void* l) {
  __builtin_amdgcn_global_load_lds((const __attribute__((address_space(1))) void*)g,
                                   (__attribute__((address_space(3))) void*)l, 16, 0, 0);
}

__device__ __forceinline__ float exp2_fast(float x) {  // 2^x via v_exp_f32
  float r; asm("v_exp_f32 %0, %1" : "=v"(r) : "v"(x)); return r;
}

__device__ __forceinline__ unsigned cvt_pk_bf16(float lo, float hi) {
  unsigned r; asm("v_cvt_pk_bf16_f32 %0, %1, %2" : "=v"(r) : "v"(lo), "v"(hi)); return r;
}

// bijective XCD-chunk swizzle (m204): XCD x gets a contiguous range of work ids
template<int NWG>
__device__ __forceinline__ int xcd_swz(int bid) {
  constexpr int q = NWG >> 3, r = NWG & 7;
  const int x = bid & 7, l = bid >> 3;
  return (x < r ? x * (q + 1) : r * (q + 1) + (x - r) * q) + l;
}

// ---------------- fused prep: convert_x | transpose W_qkv | transpose W_proj | zero_pad ---
// block ranges: [0,12144) convert_x; [12144,12576) W_qkv^T; [12576,12720) W_proj^T;
// [12720,14160) zero_pad. One launch replaces four; small jobs stream concurrently
// with convert_x's 149 MB instead of serializing behind separate dispatches.
__global__ void prep(const float* __restrict__ x, unsigned short* __restrict__ xb,
                     const float* __restrict__ W_qkv, unsigned short* __restrict__ wqkvT,
                     const float* __restrict__ W_proj, unsigned short* __restrict__ wprojT,
                     unsigned short* __restrict__ kb, unsigned short* __restrict__ vt) {
  __shared__ float tile[64][65];
  int blk = blockIdx.x;

  if (blk < 12144) {
    // ---- x fp32 -> bf16 (pad rows zeroed) ----
    const long e = ((long)blk * 256 + threadIdx.x) * 8;
    const long row = e / 768;
    s16x8 v;
    if (row < M_) {
#pragma unroll
      for (int j = 0; j < 8; ++j) v[j] = (short)f2bf(x[e + j]);
    } else {
      v = (s16x8){0,0,0,0,0,0,0,0};
    }
    *(s16x8*)&xb[e] = v;
    return;
  }
  blk -= 12144;

  if (blk < 432 + 144) {
    // ---- W [R][Ccols] fp32 -> W^T [Ccols][R] bf16 (64x64 tile via LDS) ----
    const float* in;
    unsigned short* out;
    int R, Ccols, bx, by;
    if (blk < 432) { in = W_qkv;  out = wqkvT;  R = 768; Ccols = 2304; bx = blk % 36;  by = blk / 36; }
    else { const int b2 = blk - 432;
           in = W_proj; out = wprojT; R = 768; Ccols = 768;  bx = b2 % 12;   by = b2 / 12; }
    const int tc = bx * 64, tr = by * 64;
#pragma unroll
    for (int i = 0; i < 16; ++i) {
      const int e = i * 256 + threadIdx.x;
      const int r = e >> 6, c = e & 63;
      tile[r][c] = in[(long)(tr + r) * Ccols + tc + c];
    }
    __syncthreads();
#pragma unroll
    for (int i = 0; i < 16; ++i) {
      const int e = i * 256 + threadIdx.x;
      const int c = e >> 6, r = e & 63;
      out[(long)(tc + c) * R + tr + r] = f2bf(tile[r][c]);
    }
    return;
  }
  blk -= 576;

  // ---- zero the padding tokens 1009..1023 of K and V^T ----
  const int t = blk * 256 + threadIdx.x;
  if (t >= 368640) return;                       // 384*15*64 == 24576*15
  const int d = t & 63;
  const int r = t >> 6;                          // [0,5760)
  const int bh = r / 15, tok = 1009 + (r - bh * 15);
  kb[(((long)bh << 10) + tok) * 64 + d] = 0;     // K: [BH][1024][64]
  const int c = t % 15, row = t / 15;            // row < 24576
  vt[((long)row << 10) + 1009 + c] = 0;          // V^T: [BH*64 rows][1024]
}

// ---------------- GEMM: A[M x 768] bf16 row-major, Bt[N x 768] bf16 (B^T) ----------------
// Grid: A-reuse-major (bm = swz/NBN) + bijective XCD chunking -> XCD working set L2-fits.
// K-loop: 3-slot LDS rotation, ONE barrier per K-step (r10). Per iter t:
//   vmcnt(4) [tile t landed] -> barrier -> stage slot[(t+2)%3] -> ds_read slot[t%3] -> MFMA.
// LDS tiles XOR-swizzled (chunk ^= (row>>1)&3, pre-swizzled global src) -> 2-way-free reads.
// MODE 0 epilogues through LDS (q/k coalesced 16B, q pre-scaled 0.125*log2e; V transposed).
// MODE 1: fp32 out + bias, direct.
template<int MODE>
__global__ __launch_bounds__(256, 3)
void gemm_bt(const unsigned short* __restrict__ A,
             const unsigned short* __restrict__ Bt,
             const float* __restrict__ bias,
             unsigned short* __restrict__ qo,
             unsigned short* __restrict__ ko,
             unsigned short* __restrict__ vo,
             float* __restrict__ fo) {
  // layout (bytes): slot s @ s*16384 (A 8KB | B 8KB), s=0..2; epilogue tile reuses slot 0/1
  __shared__ __align__(16) unsigned short smem[24576];   // 49152 B -> 3 blocks/CU
  const int tid = threadIdx.x;
  const int lane = tid & 63;
  const int wv = tid >> 6;
  constexpr int NBN = (MODE == 0) ? 18 : 6;
  const int swzid = xcd_swz<MT_ * NBN>(blockIdx.x);
  const int bm = swzid / NBN;
  const int bn = swzid - bm * NBN;
  const int row0 = bm * 128;
  const int col0 = bn * 128;
  const int wr = (wv >> 1) * 64;
  const int wc = (wv & 1) * 64;

  // stage one 128x32 K-step of A and B into slot (4 async16/thread)
  auto stage = [&](int slot, int kt) {
#pragma unroll
    for (int c = 0; c < 2; ++c) {
      const int lds_off = c * 4096 + wv * 1024;    // wave-uniform byte base within half
      const int gg = c * 256 + wv * 64 + lane;     // this lane's 16B granule
      const int row = gg >> 2;                     // tile row (4 granules/row)
      const int ck = ((gg & 3) ^ ((row >> 1) & 3)) << 3;  // pre-swizzled source chunk
      async16(A + (long)(row0 + row) * 768 + kt + ck, (char*)smem + slot * 16384 + lds_off);
      async16(Bt + (long)(col0 + row) * 768 + kt + ck, (char*)smem + slot * 16384 + 8192 + lds_off);
    }
  };

  f32x4 acc[4][4] = {};
  stage(0, 0);       // tile 0
  stage(1, 32);      // tile 1
  for (int it = 0; it < 24; ++it) {
    const int sl = it % 3;
    if (it + 1 < 24) {
      asm volatile("s_waitcnt vmcnt(4)" ::: "memory");   // tile it landed; it+1 may fly
    } else {
      asm volatile("s_waitcnt vmcnt(0)" ::: "memory");
    }
    __builtin_amdgcn_s_barrier();
    if (it + 2 < 24) stage((it + 2) % 3, (it + 2) * 32); // overwrite slot read at it-1 (drained)

    const unsigned short* Asb = smem + sl * 8192;           // shorts
    const unsigned short* Bsb = Asb + 4096;
    s16x8 af[4], bfr[4];
#pragma unroll
    for (int m = 0; m < 4; ++m) {
      const int rA = wr + m * 16 + (lane & 15);
      af[m] = *(const s16x8*)&Asb[rA * 32 + (((lane >> 4) ^ ((rA >> 1) & 3)) << 3)];
    }
#pragma unroll
    for (int n = 0; n < 4; ++n) {
      const int rB = wc + n * 16 + (lane & 15);
      bfr[n] = *(const s16x8*)&Bsb[rB * 32 + (((lane >> 4) ^ ((rB >> 1) & 3)) << 3)];
    }
    __builtin_amdgcn_s_setprio(1);
#pragma unroll
    for (int m = 0; m < 4; ++m)
#pragma unroll
      for (int n = 0; n < 4; ++n)
        acc[m][n] = mfma16(af[m], bfr[n], acc[m][n]);
    __builtin_amdgcn_s_setprio(0);
  }
  __syncthreads();   // all waves done with K-loop before epilogue reuses smem

  if (MODE == 0 && col0 < 1536) {
    // ---- q/k path: stage [tok 0..127][col 0..127] bf16 in LDS, then 16B stores ----
    const int qsel = col0 < 768;                 // whole block is q or k (col0 mult of 128)
#pragma unroll
    for (int m = 0; m < 4; ++m)
#pragma unroll
      for (int j = 0; j < 4; ++j)
#pragma unroll
        for (int n = 0; n < 4; ++n) {
          const int tk = wr + m * 16 + (lane >> 4) * 4 + j;
          const int cl = wc + n * 16 + (lane & 15);
          float val = acc[m][n][j] + bias[col0 + cl];
          if (qsel) val *= 0.18033688011112042f;  // 0.125 * log2(e): exp2-domain scores
          smem[tk * 136 + cl] = f2bf(val);
        }
    __syncthreads();
    unsigned short* const dst = qsel ? qo : ko;
    const int colb = col0 - (qsel ? 0 : 768);
#pragma unroll
    for (int it = 0; it < 8; ++it) {
      const int g = it * 256 + tid;
      const int tk = g >> 4;                     // local token
      const int ch = (g & 15) * 8;               // col chunk (8 shorts = 16B)
      const int grow = row0 + tk;
      if (grow < M_) {
        const s16x8 vv = *(const s16x8*)&smem[tk * 136 + ch];   // 16B aligned (272B rows)
        const int b = grow / N_;
        const int ntok = grow - b * N_;
        const int rem = colb + ch;
        const int h = rem >> 6, d = rem & 63;    // d multiple of 8 -> dest 16B aligned
        *(s16x8*)&dst[(((((long)b * H_ + h) << 10) + ntok) << 6) + d] = vv;
      }
    }
    return;
  }

  if (MODE == 0) {
    // ---- V path: stage transposed tile [d_local 0..127][tok 0..127] in LDS ----
#pragma unroll
    for (int m = 0; m < 4; ++m)
#pragma unroll
      for (int j = 0; j < 4; ++j)
#pragma unroll
        for (int n = 0; n < 4; ++n) {
          const int dl = wc + n * 16 + (lane & 15);
          const int tk = wr + m * 16 + (lane >> 4) * 4 + j;
          smem[dl * 136 + tk] = f2bf(acc[m][n][j] + bias[col0 + dl]);
        }
    __syncthreads();
    const int h0 = (col0 - 1536) >> 6;
    const int b0 = row0 / N_;
    const int split = (b0 + 1) * N_ - row0;   // block tokens [0,split) belong to batch b0
#pragma unroll
    for (int it = 0; it < 8; ++it) {
      const int g = it * 256 + tid;
      const int dl = g >> 4;
      const int t8 = (g & 15) * 8;
      const s16x8 vv = *(const s16x8*)&smem[dl * 136 + t8];   // 16B aligned
      const int hh = h0 + (dl >> 6), dd = dl & 63;
#pragma unroll
      for (int jj = 0; jj < 8; ++jj) {
        const int tkb = t8 + jj;
        const int grow = row0 + tkb;
        if (grow < M_) {
          const int bb = (tkb < split) ? b0 : b0 + 1;
          const int ntok = grow - bb * N_;
          vo[(((((long)bb * H_ + hh) << 6) + dd) << 10) + ntok] = (unsigned short)vv[jj];
        }
      }
    }
    return;
  }

  // ---- MODE 1: fp32 out + bias ----
#pragma unroll
  for (int m = 0; m < 4; ++m) {
#pragma unroll
    for (int j = 0; j < 4; ++j) {
      const int grow = row0 + wr + m * 16 + (lane >> 4) * 4 + j;
      if (grow < M_) {
#pragma unroll
        for (int n = 0; n < 4; ++n) {
          const int col = col0 + wc + n * 16 + (lane & 15);
          fo[(long)grow * 768 + col] = acc[m][n][j] + bias[col];
        }
      }
    }
  }
}

// ---------------- flash attention: block = (b, h, 64-query tile), KVBLK=64 ----------------
// SWAPPED layout: QK^T computed as mfma(K,Q) -> S^T[key][q=lane&15]; PV as mfma(V^T,P)
// -> O^T[d][q=lane&15]. Softmax state (m,l) is one scalar per lane; reductions are
// in-lane over 16 regs + 2 shfl_xor(16,32). Q pre-scaled by 0.125*log2e -> exp2 domain.
// tile==7 blocks also emit the prompt row (token 0 output = v[:,0]) -- folded misc_copy.
__global__ __launch_bounds__(256, 4)
void attn_kernel(const unsigned short* __restrict__ qg,
                 const unsigned short* __restrict__ kg,
                 const unsigned short* __restrict__ vtg,
                 unsigned short* __restrict__ og) {
  __shared__ __align__(16) unsigned short Ks[2][64 * 64];
  __shared__ __align__(16) unsigned short Vts[2][64 * 64];
  __shared__ __align__(16) unsigned short Ps[64 * 64];

  const int bid = blockIdx.x;
  const int swz = (bid & 7) * 768 + (bid >> 3);
  const int tile = swz & 15;
  const int bh = swz >> 4;
  const int b = bh / H_;
  const int h = bh - b * H_;
  int qbase, qend, kstart, ktiles, kend;
  if (tile < 7) { qbase = 1 + 64 * tile;       qend = 433;  kstart = 1; ktiles = 7;  kend = 433; }
  else          { qbase = 433 + 64 * (tile-7); qend = 1009; kstart = 0; ktiles = 16; kend = 1009; }
  const long base  = (long)bh << 10;
  const long vbase = (long)bh << 6;
  const int tid = threadIdx.x, lane = tid & 63, wv = tid >> 6;
  const int q15 = lane & 15, q7 = lane & 7, g = lane >> 4;

  // folded misc_copy: prompt segment out[b, 0, h*64+d] = v[b,h,0,d] (token 0, softmax of 1)
  if (tile == 7 && tid < 64)
    og[((long)b * N_) * 768 + h * 64 + tid] = vtg[(vbase + tid) << 10];

  s16x8 qa[2];
  {
    const unsigned short* qp = qg + (base + qbase + wv * 16 + q15) * 64;
    qa[0] = *(const s16x8*)(qp + g * 8);
    qa[1] = *(const s16x8*)(qp + 32 + g * 8);
  }
  asm volatile("s_waitcnt vmcnt(0)" ::: "memory");

  f32x4 o[4] = {};
  float mrow = -1e30f, lrow = 0.f;

  auto stage = [&](int bufsel, int kb0) {
#pragma unroll
    for (int it = 0; it < 2; ++it) {
      const int ldsoff = (it * 256 + wv * 64) * 16;
      const int gr = it * 256 + wv * 64 + lane;
      const int rl = gr >> 3;
      const int cs = (gr & 7) ^ (rl & 7);
      async16(kg + ((base + kb0 + rl) << 6) + cs * 8, (char*)&Ks[bufsel][0] + ldsoff);
      async16(vtg + ((vbase + rl) << 10) + kb0 + cs * 8, (char*)&Vts[bufsel][0] + ldsoff);
    }
  };

  const int prow = wv * 16 + q15;

  stage(0, kstart);
  for (int kt = 0; kt < ktiles; ++kt) {
    const int buf = kt & 1;
    const int kbase0 = kstart + 64 * kt;
    if (kt + 1 < ktiles) {
      stage(buf ^ 1, kbase0 + 64);
      asm volatile("s_waitcnt vmcnt(4)" ::: "memory");
    } else {
      asm volatile("s_waitcnt vmcnt(0)" ::: "memory");
    }
    __builtin_amdgcn_s_barrier();

    f32x4 s4[4];
    __builtin_amdgcn_s_setprio(1);
#pragma unroll
    for (int n = 0; n < 4; ++n) {
      const int krow = n * 16 + q15;
      const int r7 = krow & 7;
      f32x4 a = {};
      a = mfma16(*(const s16x8*)&Ks[buf][krow * 64 + ((g ^ r7) << 3)],       qa[0], a);
      a = mfma16(*(const s16x8*)&Ks[buf][krow * 64 + (((4 + g) ^ r7) << 3)], qa[1], a);
      s4[n] = a;
    }
    __builtin_amdgcn_s_setprio(0);

    if (kbase0 + 64 > kend) {
#pragma unroll
      for (int n = 0; n < 4; ++n)
#pragma unroll
        for (int j = 0; j < 4; ++j)
          if (kbase0 + n * 16 + g * 4 + j >= kend) s4[n][j] = -1e30f;
    }

    float rmax = fmaxf(
        fmaxf(fmaxf(fmaxf(s4[0][0], s4[0][1]), fmaxf(s4[0][2], s4[0][3])),
              fmaxf(fmaxf(s4[1][0], s4[1][1]), fmaxf(s4[1][2], s4[1][3]))),
        fmaxf(fmaxf(fmaxf(s4[2][0], s4[2][1]), fmaxf(s4[2][2], s4[2][3])),
              fmaxf(fmaxf(s4[3][0], s4[3][1]), fmaxf(s4[3][2], s4[3][3]))));
    rmax = fmaxf(rmax, __shfl_xor(rmax, 16));
    rmax = fmaxf(rmax, __shfl_xor(rmax, 32));

    const float mnew = fmaxf(mrow, rmax);
    const float corr = exp2_fast(mrow - mnew);
    mrow = mnew;
#pragma unroll
    for (int f = 0; f < 4; ++f)
#pragma unroll
      for (int j = 0; j < 4; ++j) o[f][j] *= corr;

    float psum = 0.f;
#pragma unroll
    for (int n = 0; n < 4; ++n) {
#pragma unroll
      for (int j = 0; j < 4; ++j) {
        s4[n][j] = exp2_fast(s4[n][j] - mnew);
        psum += s4[n][j];
      }
      uint2 pw;
      pw.x = cvt_pk_bf16(s4[n][0], s4[n][1]);
      pw.y = cvt_pk_bf16(s4[n][2], s4[n][3]);
      *(uint2*)((char*)Ps + prow * 128 + (((n * 2 + (g >> 1)) ^ q7) << 4) + (g & 1) * 8) = pw;
    }
    psum += __shfl_xor(psum, 16);
    psum += __shfl_xor(psum, 32);
    lrow = lrow * corr + psum;

    s16x8 pa[2];
#pragma unroll
    for (int kf = 0; kf < 2; ++kf)
      pa[kf] = *(const s16x8*)((char*)Ps + prow * 128 + (((kf * 4 + g) ^ q7) << 4));
    __builtin_amdgcn_s_setprio(1);
#pragma unroll
    for (int f = 0; f < 4; ++f) {
      const int vrow = f * 16 + q15;
      const int v7 = vrow & 7;
#pragma unroll
      for (int kf = 0; kf < 2; ++kf) {
        const s16x8 vb = *(const s16x8*)&Vts[buf][vrow * 64 + (((kf * 4 + g) ^ v7) << 3)];
        o[f] = mfma16(vb, pa[kf], o[f]);
      }
    }
    __builtin_amdgcn_s_setprio(0);

    asm volatile("s_waitcnt lgkmcnt(0)" ::: "memory");
    __builtin_amdgcn_s_barrier();
  }

  const int qrow = qbase + wv * 16 + q15;
  if (qrow < qend) {
    const float inv = 1.0f / lrow;
    unsigned short* op = og + ((long)b * N_ + qrow) * 768 + h * 64 + g * 4;
#pragma unroll
    for (int f = 0; f < 4; ++f) {
      uint2 ow;
      ow.x = cvt_pk_bf16(o[f][0] * inv, o[f][1] * inv);
      ow.y = cvt_pk_bf16(o[f][2] * inv, o[f][3] * inv);
      *(uint2*)(op + f * 16) = ow;
    }
  }
}

extern "C" void kernel_launch(void* const* d_in, const int* in_sizes, int n_in,
                              void* d_out, int out_size, void* d_ws, size_t ws_size,
                              hipStream_t stream) {
  const float* x      = (const float*)d_in[0];
  const float* W_qkv  = (const float*)d_in[1];
  const float* b_qkv  = (const float*)d_in[2];
  const float* W_proj = (const float*)d_in[3];
  const float* b_proj = (const float*)d_in[4];
  float* out = (float*)d_out;

  unsigned short* ws = (unsigned short*)d_ws;
  unsigned short* wqkvT  = ws;                                  // [2304][768] bf16
  unsigned short* wprojT = wqkvT + (long)2304 * 768;            // [768][768] bf16
  unsigned short* qb = wprojT + (long)768 * 768;                // [B][H][1024][64] bf16
  const long kvsz = (long)B_ * H_ * NKV_ * D_;
  unsigned short* kb = qb + kvsz;                               // [B][H][1024][64] bf16
  unsigned short* vb = kb + kvsz;                               // V^T: [B][H][64][1024] bf16
  unsigned short* xb = vb + kvsz;                               // [MPAD][768] bf16
  unsigned short* attnout = xb;  // aliased: xb dead after QKV GEMM (stream-ordered)

  prep<<<14160, 256, 0, stream>>>(x, xb, W_qkv, wqkvT, W_proj, wprojT, kb, vb);
  gemm_bt<0><<<MT_ * 18, 256, 0, stream>>>(xb, wqkvT, b_qkv, qb, kb, vb, nullptr);
  attn_kernel<<<B_ * H_ * 16, 256, 0, stream>>>(qb, kb, vb, attnout);
  gemm_bt<1><<<MT_ * 6, 256, 0, stream>>>(attnout, wprojT, b_proj, nullptr, nullptr, nullptr, out);
}

// Round 12
// 393.601 us; speedup vs baseline: 1.0556x; 1.0062x over previous
//
#include <hip/hip_runtime.h>

#define B_ 32
#define N_ 1009
#define C_ 768
#define H_ 12
#define D_ 64
#define M_ (B_*N_)          // 32288 tokens
#define MT_ 253             // ceil(M/128)
#define MPAD_ (MT_*128)     // 32384
#define NKV_ 1024           // padded sequence length for q/k/v storage

typedef __attribute__((ext_vector_type(4))) float f32x4;
typedef __attribute__((ext_vector_type(8))) short s16x8;

__device__ __forceinline__ unsigned short f2bf(float f) {
  union { float f; unsigned u; } x; x.f = f;
  unsigned r = x.u + 0x7fffu + ((x.u >> 16) & 1u);
  return (unsigned short)(r >> 16);
}

__device__ __forceinline__ f32x4 mfma16(s16x8 a, s16x8 b, f32x4 c) {
  return __builtin_amdgcn_mfma_f32_16x16x32_bf16(a, b, c, 0, 0, 0);
}

__device__ __forceinline__ void async16(const void* g, void* l) {
  __builtin_amdgcn_global_load_lds((const __attribute__((address_space(1))) void*)g,
                                   (__attribute__((address_space(3))) void*)l, 16, 0, 0);
}

__device__ __forceinline__ float exp2_fast(float x) {  // 2^x via v_exp_f32
  float r; asm("v_exp_f32 %0, %1" : "=v"(r) : "v"(x)); return r;
}

__device__ __forceinline__ unsigned cvt_pk_bf16(float lo, float hi) {
  unsigned r; asm("v_cvt_pk_bf16_f32 %0, %1, %2" : "=v"(r) : "v"(lo), "v"(hi)); return r;
}

// bijective XCD-chunk swizzle (m204): XCD x gets a contiguous range of work ids
template<int NWG>
__device__ __forceinline__ int xcd_swz(int bid) {
  constexpr int q = NWG >> 3, r = NWG & 7;
  const int x = bid & 7, l = bid >> 3;
  return (x < r ? x * (q + 1) : r * (q + 1) + (x - r) * q) + l;
}

// ---------------- fused prep: convert_x | transpose W_qkv | transpose W_proj | zero_pad ---
// block ranges: [0,12144) convert_x; [12144,12576) W_qkv^T; [12576,12720) W_proj^T;
// [12720,14160) zero_pad. One launch replaces four; small jobs stream concurrently
// with convert_x's 149 MB instead of serializing behind separate dispatches.
__global__ void prep(const float* __restrict__ x, unsigned short* __restrict__ xb,
                     const float* __restrict__ W_qkv, unsigned short* __restrict__ wqkvT,
                     const float* __restrict__ W_proj, unsigned short* __restrict__ wprojT,
                     unsigned short* __restrict__ kb, unsigned short* __restrict__ vt) {
  __shared__ float tile[64][65];
  int blk = blockIdx.x;

  if (blk < 12144) {
    // ---- x fp32 -> bf16 (pad rows zeroed) ----
    const long e = ((long)blk * 256 + threadIdx.x) * 8;
    const long row = e / 768;
    s16x8 v;
    if (row < M_) {
#pragma unroll
      for (int j = 0; j < 8; ++j) v[j] = (short)f2bf(x[e + j]);
    } else {
      v = (s16x8){0,0,0,0,0,0,0,0};
    }
    *(s16x8*)&xb[e] = v;
    return;
  }
  blk -= 12144;

  if (blk < 432 + 144) {
    // ---- W [R][Ccols] fp32 -> W^T [Ccols][R] bf16 (64x64 tile via LDS) ----
    const float* in;
    unsigned short* out;
    int R, Ccols, bx, by;
    if (blk < 432) { in = W_qkv;  out = wqkvT;  R = 768; Ccols = 2304; bx = blk % 36;  by = blk / 36; }
    else { const int b2 = blk - 432;
           in = W_proj; out = wprojT; R = 768; Ccols = 768;  bx = b2 % 12;   by = b2 / 12; }
    const int tc = bx * 64, tr = by * 64;
#pragma unroll
    for (int i = 0; i < 16; ++i) {
      const int e = i * 256 + threadIdx.x;
      const int r = e >> 6, c = e & 63;
      tile[r][c] = in[(long)(tr + r) * Ccols + tc + c];
    }
    __syncthreads();
#pragma unroll
    for (int i = 0; i < 16; ++i) {
      const int e = i * 256 + threadIdx.x;
      const int c = e >> 6, r = e & 63;
      out[(long)(tc + c) * R + tr + r] = f2bf(tile[r][c]);
    }
    return;
  }
  blk -= 576;

  // ---- zero the padding tokens 1009..1023 of K and V^T ----
  const int t = blk * 256 + threadIdx.x;
  if (t >= 368640) return;                       // 384*15*64 == 24576*15
  const int d = t & 63;
  const int r = t >> 6;                          // [0,5760)
  const int bh = r / 15, tok = 1009 + (r - bh * 15);
  kb[(((long)bh << 10) + tok) * 64 + d] = 0;     // K: [BH][1024][64]
  const int c = t % 15, row = t / 15;            // row < 24576
  vt[((long)row << 10) + 1009 + c] = 0;          // V^T: [BH*64 rows][1024]
}

// ---------------- GEMM: A[M x 768] bf16 row-major, Bt[N x 768] bf16 (B^T) ----------------
// Grid: A-reuse-major (bm = swz/NBN) + bijective XCD chunking -> XCD working set L2-fits.
// K-loop: 3-slot LDS rotation, ONE barrier per K-step (r10). Per iter t:
//   vmcnt(4) [tile t landed] -> barrier -> stage slot[(t+2)%3] -> ds_read slot[t%3] -> MFMA.
// LDS tiles XOR-swizzled (chunk ^= (row>>1)&3, pre-swizzled global src) -> 2-way-free reads.
// MODE 0 epilogues through LDS (q/k coalesced 16B, q pre-scaled 0.125*log2e; V transposed).
// MODE 1: fp32 out + bias, direct.
template<int MODE>
__global__ __launch_bounds__(256, 3)
void gemm_bt(const unsigned short* __restrict__ A,
             const unsigned short* __restrict__ Bt,
             const float* __restrict__ bias,
             unsigned short* __restrict__ qo,
             unsigned short* __restrict__ ko,
             unsigned short* __restrict__ vo,
             float* __restrict__ fo) {
  // layout (bytes): slot s @ s*16384 (A 8KB | B 8KB), s=0..2; epilogue tile reuses slot 0/1
  __shared__ __align__(16) unsigned short smem[24576];   // 49152 B -> 3 blocks/CU
  const int tid = threadIdx.x;
  const int lane = tid & 63;
  const int wv = tid >> 6;
  constexpr int NBN = (MODE == 0) ? 18 : 6;
  const int swzid = xcd_swz<MT_ * NBN>(blockIdx.x);
  const int bm = swzid / NBN;
  const int bn = swzid - bm * NBN;
  const int row0 = bm * 128;
  const int col0 = bn * 128;
  const int wr = (wv >> 1) * 64;
  const int wc = (wv & 1) * 64;

  // stage one 128x32 K-step of A and B into slot (4 async16/thread)
  auto stage = [&](int slot, int kt) {
#pragma unroll
    for (int c = 0; c < 2; ++c) {
      const int lds_off = c * 4096 + wv * 1024;    // wave-uniform byte base within half
      const int gg = c * 256 + wv * 64 + lane;     // this lane's 16B granule
      const int row = gg >> 2;                     // tile row (4 granules/row)
      const int ck = ((gg & 3) ^ ((row >> 1) & 3)) << 3;  // pre-swizzled source chunk
      async16(A + (long)(row0 + row) * 768 + kt + ck, (char*)smem + slot * 16384 + lds_off);
      async16(Bt + (long)(col0 + row) * 768 + kt + ck, (char*)smem + slot * 16384 + 8192 + lds_off);
    }
  };

  f32x4 acc[4][4] = {};
  stage(0, 0);       // tile 0
  stage(1, 32);      // tile 1
  for (int it = 0; it < 24; ++it) {
    const int sl = it % 3;
    if (it + 1 < 24) {
      asm volatile("s_waitcnt vmcnt(4)" ::: "memory");   // tile it landed; it+1 may fly
    } else {
      asm volatile("s_waitcnt vmcnt(0)" ::: "memory");
    }
    __builtin_amdgcn_s_barrier();
    if (it + 2 < 24) stage((it + 2) % 3, (it + 2) * 32); // overwrite slot read at it-1 (drained)

    const unsigned short* Asb = smem + sl * 8192;           // shorts
    const unsigned short* Bsb = Asb + 4096;
    s16x8 af[4], bfr[4];
#pragma unroll
    for (int m = 0; m < 4; ++m) {
      const int rA = wr + m * 16 + (lane & 15);
      af[m] = *(const s16x8*)&Asb[rA * 32 + (((lane >> 4) ^ ((rA >> 1) & 3)) << 3)];
    }
#pragma unroll
    for (int n = 0; n < 4; ++n) {
      const int rB = wc + n * 16 + (lane & 15);
      bfr[n] = *(const s16x8*)&Bsb[rB * 32 + (((lane >> 4) ^ ((rB >> 1) & 3)) << 3)];
    }
    __builtin_amdgcn_s_setprio(1);
#pragma unroll
    for (int m = 0; m < 4; ++m)
#pragma unroll
      for (int n = 0; n < 4; ++n)
        acc[m][n] = mfma16(af[m], bfr[n], acc[m][n]);
    __builtin_amdgcn_s_setprio(0);
  }
  __syncthreads();   // all waves done with K-loop before epilogue reuses smem

  if (MODE == 0 && col0 < 1536) {
    // ---- q/k path: stage [tok 0..127][col 0..127] bf16 in LDS, then 16B stores ----
    const int qsel = col0 < 768;                 // whole block is q or k (col0 mult of 128)
#pragma unroll
    for (int m = 0; m < 4; ++m)
#pragma unroll
      for (int j = 0; j < 4; ++j)
#pragma unroll
        for (int n = 0; n < 4; ++n) {
          const int tk = wr + m * 16 + (lane >> 4) * 4 + j;
          const int cl = wc + n * 16 + (lane & 15);
          float val = acc[m][n][j] + bias[col0 + cl];
          if (qsel) val *= 0.18033688011112042f;  // 0.125 * log2(e): exp2-domain scores
          smem[tk * 136 + cl] = f2bf(val);
        }
    __syncthreads();
    unsigned short* const dst = qsel ? qo : ko;
    const int colb = col0 - (qsel ? 0 : 768);
#pragma unroll
    for (int it = 0; it < 8; ++it) {
      const int g = it * 256 + tid;
      const int tk = g >> 4;                     // local token
      const int ch = (g & 15) * 8;               // col chunk (8 shorts = 16B)
      const int grow = row0 + tk;
      if (grow < M_) {
        const s16x8 vv = *(const s16x8*)&smem[tk * 136 + ch];   // 16B aligned (272B rows)
        const int b = grow / N_;
        const int ntok = grow - b * N_;
        const int rem = colb + ch;
        const int h = rem >> 6, d = rem & 63;    // d multiple of 8 -> dest 16B aligned
        *(s16x8*)&dst[(((((long)b * H_ + h) << 10) + ntok) << 6) + d] = vv;
      }
    }
    return;
  }

  if (MODE == 0) {
    // ---- V path: stage transposed tile [d_local 0..127][tok 0..127] in LDS ----
#pragma unroll
    for (int m = 0; m < 4; ++m)
#pragma unroll
      for (int j = 0; j < 4; ++j)
#pragma unroll
        for (int n = 0; n < 4; ++n) {
          const int dl = wc + n * 16 + (lane & 15);
          const int tk = wr + m * 16 + (lane >> 4) * 4 + j;
          smem[dl * 136 + tk] = f2bf(acc[m][n][j] + bias[col0 + dl]);
        }
    __syncthreads();
    const int h0 = (col0 - 1536) >> 6;
    const int b0 = row0 / N_;
    const int split = (b0 + 1) * N_ - row0;   // block tokens [0,split) belong to batch b0
#pragma unroll
    for (int it = 0; it < 8; ++it) {
      const int g = it * 256 + tid;
      const int dl = g >> 4;
      const int t8 = (g & 15) * 8;
      const s16x8 vv = *(const s16x8*)&smem[dl * 136 + t8];   // 16B aligned
      const int hh = h0 + (dl >> 6), dd = dl & 63;
#pragma unroll
      for (int jj = 0; jj < 8; ++jj) {
        const int tkb = t8 + jj;
        const int grow = row0 + tkb;
        if (grow < M_) {
          const int bb = (tkb < split) ? b0 : b0 + 1;
          const int ntok = grow - bb * N_;
          vo[(((((long)bb * H_ + hh) << 6) + dd) << 10) + ntok] = (unsigned short)vv[jj];
        }
      }
    }
    return;
  }

  // ---- MODE 1: fp32 out + bias ----
#pragma unroll
  for (int m = 0; m < 4; ++m) {
#pragma unroll
    for (int j = 0; j < 4; ++j) {
      const int grow = row0 + wr + m * 16 + (lane >> 4) * 4 + j;
      if (grow < M_) {
#pragma unroll
        for (int n = 0; n < 4; ++n) {
          const int col = col0 + wc + n * 16 + (lane & 15);
          fo[(long)grow * 768 + col] = acc[m][n][j] + bias[col];
        }
      }
    }
  }
}

// ---------------- flash attention: block = (b, h, 64-query tile), KVBLK=64 ----------------
// SWAPPED layout: QK^T computed as mfma(K,Q) -> S^T[key][q=lane&15]; PV as mfma(V^T,P)
// -> O^T[d][q=lane&15]. Softmax state (m,l) is one scalar per lane; reductions are
// in-lane over 16 regs + 2 shfl_xor(16,32). Q pre-scaled by 0.125*log2e -> exp2 domain.
// Defer-max (T13, THR=8 log2-domain, P <= 2^8): skip corr+rescale when the wave's 16
// q-rows are all within THR of the running max. First tile always rescales (mrow=-1e30).
// tile==7 blocks also emit the prompt row (token 0 output = v[:,0]) -- folded misc_copy.
__global__ __launch_bounds__(256, 4)
void attn_kernel(const unsigned short* __restrict__ qg,
                 const unsigned short* __restrict__ kg,
                 const unsigned short* __restrict__ vtg,
                 unsigned short* __restrict__ og) {
  __shared__ __align__(16) unsigned short Ks[2][64 * 64];
  __shared__ __align__(16) unsigned short Vts[2][64 * 64];
  __shared__ __align__(16) unsigned short Ps[64 * 64];

  const int bid = blockIdx.x;
  const int swz = (bid & 7) * 768 + (bid >> 3);
  const int tile = swz & 15;
  const int bh = swz >> 4;
  const int b = bh / H_;
  const int h = bh - b * H_;
  int qbase, qend, kstart, ktiles, kend;
  if (tile < 7) { qbase = 1 + 64 * tile;       qend = 433;  kstart = 1; ktiles = 7;  kend = 433; }
  else          { qbase = 433 + 64 * (tile-7); qend = 1009; kstart = 0; ktiles = 16; kend = 1009; }
  const long base  = (long)bh << 10;
  const long vbase = (long)bh << 6;
  const int tid = threadIdx.x, lane = tid & 63, wv = tid >> 6;
  const int q15 = lane & 15, q7 = lane & 7, g = lane >> 4;

  // folded misc_copy: prompt segment out[b, 0, h*64+d] = v[b,h,0,d] (token 0, softmax of 1)
  if (tile == 7 && tid < 64)
    og[((long)b * N_) * 768 + h * 64 + tid] = vtg[(vbase + tid) << 10];

  s16x8 qa[2];
  {
    const unsigned short* qp = qg + (base + qbase + wv * 16 + q15) * 64;
    qa[0] = *(const s16x8*)(qp + g * 8);
    qa[1] = *(const s16x8*)(qp + 32 + g * 8);
  }
  asm volatile("s_waitcnt vmcnt(0)" ::: "memory");

  f32x4 o[4] = {};
  float mrow = -1e30f, lrow = 0.f;

  auto stage = [&](int bufsel, int kb0) {
#pragma unroll
    for (int it = 0; it < 2; ++it) {
      const int ldsoff = (it * 256 + wv * 64) * 16;
      const int gr = it * 256 + wv * 64 + lane;
      const int rl = gr >> 3;
      const int cs = (gr & 7) ^ (rl & 7);
      async16(kg + ((base + kb0 + rl) << 6) + cs * 8, (char*)&Ks[bufsel][0] + ldsoff);
      async16(vtg + ((vbase + rl) << 10) + kb0 + cs * 8, (char*)&Vts[bufsel][0] + ldsoff);
    }
  };

  const int prow = wv * 16 + q15;

  stage(0, kstart);
  for (int kt = 0; kt < ktiles; ++kt) {
    const int buf = kt & 1;
    const int kbase0 = kstart + 64 * kt;
    if (kt + 1 < ktiles) {
      stage(buf ^ 1, kbase0 + 64);
      asm volatile("s_waitcnt vmcnt(4)" ::: "memory");
    } else {
      asm volatile("s_waitcnt vmcnt(0)" ::: "memory");
    }
    __builtin_amdgcn_s_barrier();

    f32x4 s4[4];
    __builtin_amdgcn_s_setprio(1);
#pragma unroll
    for (int n = 0; n < 4; ++n) {
      const int krow = n * 16 + q15;
      const int r7 = krow & 7;
      f32x4 a = {};
      a = mfma16(*(const s16x8*)&Ks[buf][krow * 64 + ((g ^ r7) << 3)],       qa[0], a);
      a = mfma16(*(const s16x8*)&Ks[buf][krow * 64 + (((4 + g) ^ r7) << 3)], qa[1], a);
      s4[n] = a;
    }
    __builtin_amdgcn_s_setprio(0);

    if (kbase0 + 64 > kend) {
#pragma unroll
      for (int n = 0; n < 4; ++n)
#pragma unroll
        for (int j = 0; j < 4; ++j)
          if (kbase0 + n * 16 + g * 4 + j >= kend) s4[n][j] = -1e30f;
    }

    float rmax = fmaxf(
        fmaxf(fmaxf(fmaxf(s4[0][0], s4[0][1]), fmaxf(s4[0][2], s4[0][3])),
              fmaxf(fmaxf(s4[1][0], s4[1][1]), fmaxf(s4[1][2], s4[1][3]))),
        fmaxf(fmaxf(fmaxf(s4[2][0], s4[2][1]), fmaxf(s4[2][2], s4[2][3])),
              fmaxf(fmaxf(s4[3][0], s4[3][1]), fmaxf(s4[3][2], s4[3][3]))));
    rmax = fmaxf(rmax, __shfl_xor(rmax, 16));
    rmax = fmaxf(rmax, __shfl_xor(rmax, 32));   // uniform across the 4 lane-groups per q

    // defer-max (T13): rescale only when some q-row exceeded the slack THR=8
    if (!__all(rmax <= mrow + 8.f)) {
      const float mnew = fmaxf(mrow, rmax);
      const float corr = exp2_fast(mrow - mnew);
      mrow = mnew;
      lrow *= corr;
#pragma unroll
      for (int f = 0; f < 4; ++f)
#pragma unroll
        for (int j = 0; j < 4; ++j) o[f][j] *= corr;
    }
    const float mnew = mrow;

    float psum = 0.f;
#pragma unroll
    for (int n = 0; n < 4; ++n) {
#pragma unroll
      for (int j = 0; j < 4; ++j) {
        s4[n][j] = exp2_fast(s4[n][j] - mnew);
        psum += s4[n][j];
      }
      uint2 pw;
      pw.x = cvt_pk_bf16(s4[n][0], s4[n][1]);
      pw.y = cvt_pk_bf16(s4[n][2], s4[n][3]);
      *(uint2*)((char*)Ps + prow * 128 + (((n * 2 + (g >> 1)) ^ q7) << 4) + (g & 1) * 8) = pw;
    }
    psum += __shfl_xor(psum, 16);
    psum += __shfl_xor(psum, 32);
    lrow += psum;

    s16x8 pa[2];
#pragma unroll
    for (int kf = 0; kf < 2; ++kf)
      pa[kf] = *(const s16x8*)((char*)Ps + prow * 128 + (((kf * 4 + g) ^ q7) << 4));
    __builtin_amdgcn_s_setprio(1);
#pragma unroll
    for (int f = 0; f < 4; ++f) {
      const int vrow = f * 16 + q15;
      const int v7 = vrow & 7;
#pragma unroll
      for (int kf = 0; kf < 2; ++kf) {
        const s16x8 vb = *(const s16x8*)&Vts[buf][vrow * 64 + (((kf * 4 + g) ^ v7) << 3)];
        o[f] = mfma16(vb, pa[kf], o[f]);
      }
    }
    __builtin_amdgcn_s_setprio(0);

    asm volatile("s_waitcnt lgkmcnt(0)" ::: "memory");
    __builtin_amdgcn_s_barrier();
  }

  const int qrow = qbase + wv * 16 + q15;
  if (qrow < qend) {
    const float inv = 1.0f / lrow;
    unsigned short* op = og + ((long)b * N_ + qrow) * 768 + h * 64 + g * 4;
#pragma unroll
    for (int f = 0; f < 4; ++f) {
      uint2 ow;
      ow.x = cvt_pk_bf16(o[f][0] * inv, o[f][1] * inv);
      ow.y = cvt_pk_bf16(o[f][2] * inv, o[f][3] * inv);
      *(uint2*)(op + f * 16) = ow;
    }
  }
}

extern "C" void kernel_launch(void* const* d_in, const int* in_sizes, int n_in,
                              void* d_out, int out_size, void* d_ws, size_t ws_size,
                              hipStream_t stream) {
  const float* x      = (const float*)d_in[0];
  const float* W_qkv  = (const float*)d_in[1];
  const float* b_qkv  = (const float*)d_in[2];
  const float* W_proj = (const float*)d_in[3];
  const float* b_proj = (const float*)d_in[4];
  float* out = (float*)d_out;

  unsigned short* ws = (unsigned short*)d_ws;
  unsigned short* wqkvT  = ws;                                  // [2304][768] bf16
  unsigned short* wprojT = wqkvT + (long)2304 * 768;            // [768][768] bf16
  unsigned short* qb = wprojT + (long)768 * 768;                // [B][H][1024][64] bf16
  const long kvsz = (long)B_ * H_ * NKV_ * D_;
  unsigned short* kb = qb + kvsz;                               // [B][H][1024][64] bf16
  unsigned short* vb = kb + kvsz;                               // V^T: [B][H][64][1024] bf16
  unsigned short* xb = vb + kvsz;                               // [MPAD][768] bf16
  unsigned short* attnout = xb;  // aliased: xb dead after QKV GEMM (stream-ordered)

  prep<<<14160, 256, 0, stream>>>(x, xb, W_qkv, wqkvT, W_proj, wprojT, kb, vb);
  gemm_bt<0><<<MT_ * 18, 256, 0, stream>>>(xb, wqkvT, b_qkv, qb, kb, vb, nullptr);
  attn_kernel<<<B_ * H_ * 16, 256, 0, stream>>>(qb, kb, vb, attnout);
  gemm_bt<1><<<MT_ * 6, 256, 0, stream>>>(attnout, wprojT, b_proj, nullptr, nullptr, nullptr, out);
}

// Round 13
// 389.669 us; speedup vs baseline: 1.0663x; 1.0101x over previous
//
#include <hip/hip_runtime.h>

#define B_ 32
#define N_ 1009
#define C_ 768
#define H_ 12
#define D_ 64
#define M_ (B_*N_)          // 32288 tokens
#define MT_ 253             // ceil(M/128)
#define MPAD_ (MT_*128)     // 32384
#define NKV_ 1024           // padded sequence length for q/k/v storage

typedef __attribute__((ext_vector_type(4))) float f32x4;
typedef __attribute__((ext_vector_type(8))) short s16x8;

__device__ __forceinline__ unsigned short f2bf(float f) {
  union { float f; unsigned u; } x; x.f = f;
  unsigned r = x.u + 0x7fffu + ((x.u >> 16) & 1u);
  return (unsigned short)(r >> 16);
}

__device__ __forceinline__ f32x4 mfma16(s16x8 a, s16x8 b, f32x4 c) {
  return __builtin_amdgcn_mfma_f32_16x16x32_bf16(a, b, c, 0, 0, 0);
}

__device__ __forceinline__ void async16(const void* g, void* l) {
  __builtin_amdgcn_global_load_lds((const __attribute__((address_space(1))) void*)g,
                                   (__attribute__((address_space(3))) void*)l, 16, 0, 0);
}

__device__ __forceinline__ float exp2_fast(float x) {  // 2^x via v_exp_f32
  float r; asm("v_exp_f32 %0, %1" : "=v"(r) : "v"(x)); return r;
}

__device__ __forceinline__ unsigned cvt_pk_bf16(float lo, float hi) {
  unsigned r; asm("v_cvt_pk_bf16_f32 %0, %1, %2" : "=v"(r) : "v"(lo), "v"(hi)); return r;
}

// bijective XCD-chunk swizzle (m204): XCD x gets a contiguous range of work ids
template<int NWG>
__device__ __forceinline__ int xcd_swz(int bid) {
  constexpr int q = NWG >> 3, r = NWG & 7;
  const int x = bid & 7, l = bid >> 3;
  return (x < r ? x * (q + 1) : r * (q + 1) + (x - r) * q) + l;
}

// ---------------- fused prep: convert_x | transpose W_qkv | transpose W_proj | zero_pad ---
__global__ void prep(const float* __restrict__ x, unsigned short* __restrict__ xb,
                     const float* __restrict__ W_qkv, unsigned short* __restrict__ wqkvT,
                     const float* __restrict__ W_proj, unsigned short* __restrict__ wprojT,
                     unsigned short* __restrict__ kb, unsigned short* __restrict__ vt) {
  __shared__ float tile[64][65];
  int blk = blockIdx.x;

  if (blk < 12144) {
    // ---- x fp32 -> bf16 (pad rows zeroed) ----
    const long e = ((long)blk * 256 + threadIdx.x) * 8;
    const long row = e / 768;
    s16x8 v;
    if (row < M_) {
#pragma unroll
      for (int j = 0; j < 8; ++j) v[j] = (short)f2bf(x[e + j]);
    } else {
      v = (s16x8){0,0,0,0,0,0,0,0};
    }
    *(s16x8*)&xb[e] = v;
    return;
  }
  blk -= 12144;

  if (blk < 432 + 144) {
    // ---- W [R][Ccols] fp32 -> W^T [Ccols][R] bf16 (64x64 tile via LDS) ----
    const float* in;
    unsigned short* out;
    int R, Ccols, bx, by;
    if (blk < 432) { in = W_qkv;  out = wqkvT;  R = 768; Ccols = 2304; bx = blk % 36;  by = blk / 36; }
    else { const int b2 = blk - 432;
           in = W_proj; out = wprojT; R = 768; Ccols = 768;  bx = b2 % 12;   by = b2 / 12; }
    const int tc = bx * 64, tr = by * 64;
#pragma unroll
    for (int i = 0; i < 16; ++i) {
      const int e = i * 256 + threadIdx.x;
      const int r = e >> 6, c = e & 63;
      tile[r][c] = in[(long)(tr + r) * Ccols + tc + c];
    }
    __syncthreads();
#pragma unroll
    for (int i = 0; i < 16; ++i) {
      const int e = i * 256 + threadIdx.x;
      const int c = e >> 6, r = e & 63;
      out[(long)(tc + c) * R + tr + r] = f2bf(tile[r][c]);
    }
    return;
  }
  blk -= 576;

  // ---- zero the padding tokens 1009..1023 of K and V^T ----
  const int t = blk * 256 + threadIdx.x;
  if (t >= 368640) return;                       // 384*15*64 == 24576*15
  const int d = t & 63;
  const int r = t >> 6;                          // [0,5760)
  const int bh = r / 15, tok = 1009 + (r - bh * 15);
  kb[(((long)bh << 10) + tok) * 64 + d] = 0;     // K: [BH][1024][64]
  const int c = t % 15, row = t / 15;            // row < 24576
  vt[((long)row << 10) + 1009 + c] = 0;          // V^T: [BH*64 rows][1024]
}

// ---------------- GEMM: A[M x 768] bf16 row-major, Bt[N x 768] bf16 (B^T) ----------------
// (round-10/11 structure, unchanged: 3-slot LDS rotation, 1 barrier/K-step, counted vmcnt,
//  XOR-swizzled tiles, LDS-staged epilogues)
template<int MODE>
__global__ __launch_bounds__(256, 3)
void gemm_bt(const unsigned short* __restrict__ A,
             const unsigned short* __restrict__ Bt,
             const float* __restrict__ bias,
             unsigned short* __restrict__ qo,
             unsigned short* __restrict__ ko,
             unsigned short* __restrict__ vo,
             float* __restrict__ fo) {
  __shared__ __align__(16) unsigned short smem[24576];   // 49152 B -> 3 blocks/CU
  const int tid = threadIdx.x;
  const int lane = tid & 63;
  const int wv = tid >> 6;
  constexpr int NBN = (MODE == 0) ? 18 : 6;
  const int swzid = xcd_swz<MT_ * NBN>(blockIdx.x);
  const int bm = swzid / NBN;
  const int bn = swzid - bm * NBN;
  const int row0 = bm * 128;
  const int col0 = bn * 128;
  const int wr = (wv >> 1) * 64;
  const int wc = (wv & 1) * 64;

  auto stage = [&](int slot, int kt) {
#pragma unroll
    for (int c = 0; c < 2; ++c) {
      const int lds_off = c * 4096 + wv * 1024;
      const int gg = c * 256 + wv * 64 + lane;
      const int row = gg >> 2;
      const int ck = ((gg & 3) ^ ((row >> 1) & 3)) << 3;
      async16(A + (long)(row0 + row) * 768 + kt + ck, (char*)smem + slot * 16384 + lds_off);
      async16(Bt + (long)(col0 + row) * 768 + kt + ck, (char*)smem + slot * 16384 + 8192 + lds_off);
    }
  };

  f32x4 acc[4][4] = {};
  stage(0, 0);
  stage(1, 32);
  for (int it = 0; it < 24; ++it) {
    const int sl = it % 3;
    if (it + 1 < 24) {
      asm volatile("s_waitcnt vmcnt(4)" ::: "memory");
    } else {
      asm volatile("s_waitcnt vmcnt(0)" ::: "memory");
    }
    __builtin_amdgcn_s_barrier();
    if (it + 2 < 24) stage((it + 2) % 3, (it + 2) * 32);

    const unsigned short* Asb = smem + sl * 8192;
    const unsigned short* Bsb = Asb + 4096;
    s16x8 af[4], bfr[4];
#pragma unroll
    for (int m = 0; m < 4; ++m) {
      const int rA = wr + m * 16 + (lane & 15);
      af[m] = *(const s16x8*)&Asb[rA * 32 + (((lane >> 4) ^ ((rA >> 1) & 3)) << 3)];
    }
#pragma unroll
    for (int n = 0; n < 4; ++n) {
      const int rB = wc + n * 16 + (lane & 15);
      bfr[n] = *(const s16x8*)&Bsb[rB * 32 + (((lane >> 4) ^ ((rB >> 1) & 3)) << 3)];
    }
    __builtin_amdgcn_s_setprio(1);
#pragma unroll
    for (int m = 0; m < 4; ++m)
#pragma unroll
      for (int n = 0; n < 4; ++n)
        acc[m][n] = mfma16(af[m], bfr[n], acc[m][n]);
    __builtin_amdgcn_s_setprio(0);
  }
  __syncthreads();

  if (MODE == 0 && col0 < 1536) {
    const int qsel = col0 < 768;
#pragma unroll
    for (int m = 0; m < 4; ++m)
#pragma unroll
      for (int j = 0; j < 4; ++j)
#pragma unroll
        for (int n = 0; n < 4; ++n) {
          const int tk = wr + m * 16 + (lane >> 4) * 4 + j;
          const int cl = wc + n * 16 + (lane & 15);
          float val = acc[m][n][j] + bias[col0 + cl];
          if (qsel) val *= 0.18033688011112042f;  // 0.125 * log2(e)
          smem[tk * 136 + cl] = f2bf(val);
        }
    __syncthreads();
    unsigned short* const dst = qsel ? qo : ko;
    const int colb = col0 - (qsel ? 0 : 768);
#pragma unroll
    for (int it = 0; it < 8; ++it) {
      const int g = it * 256 + tid;
      const int tk = g >> 4;
      const int ch = (g & 15) * 8;
      const int grow = row0 + tk;
      if (grow < M_) {
        const s16x8 vv = *(const s16x8*)&smem[tk * 136 + ch];
        const int b = grow / N_;
        const int ntok = grow - b * N_;
        const int rem = colb + ch;
        const int h = rem >> 6, d = rem & 63;
        *(s16x8*)&dst[(((((long)b * H_ + h) << 10) + ntok) << 6) + d] = vv;
      }
    }
    return;
  }

  if (MODE == 0) {
#pragma unroll
    for (int m = 0; m < 4; ++m)
#pragma unroll
      for (int j = 0; j < 4; ++j)
#pragma unroll
        for (int n = 0; n < 4; ++n) {
          const int dl = wc + n * 16 + (lane & 15);
          const int tk = wr + m * 16 + (lane >> 4) * 4 + j;
          smem[dl * 136 + tk] = f2bf(acc[m][n][j] + bias[col0 + dl]);
        }
    __syncthreads();
    const int h0 = (col0 - 1536) >> 6;
    const int b0 = row0 / N_;
    const int split = (b0 + 1) * N_ - row0;
#pragma unroll
    for (int it = 0; it < 8; ++it) {
      const int g = it * 256 + tid;
      const int dl = g >> 4;
      const int t8 = (g & 15) * 8;
      const s16x8 vv = *(const s16x8*)&smem[dl * 136 + t8];
      const int hh = h0 + (dl >> 6), dd = dl & 63;
#pragma unroll
      for (int jj = 0; jj < 8; ++jj) {
        const int tkb = t8 + jj;
        const int grow = row0 + tkb;
        if (grow < M_) {
          const int bb = (tkb < split) ? b0 : b0 + 1;
          const int ntok = grow - bb * N_;
          vo[(((((long)bb * H_ + hh) << 6) + dd) << 10) + ntok] = (unsigned short)vv[jj];
        }
      }
    }
    return;
  }

#pragma unroll
  for (int m = 0; m < 4; ++m) {
#pragma unroll
    for (int j = 0; j < 4; ++j) {
      const int grow = row0 + wr + m * 16 + (lane >> 4) * 4 + j;
      if (grow < M_) {
#pragma unroll
        for (int n = 0; n < 4; ++n) {
          const int col = col0 + wc + n * 16 + (lane & 15);
          fo[(long)grow * 768 + col] = acc[m][n][j] + bias[col];
        }
      }
    }
  }
}

// ---------------- flash attention: block = (b, h, PAIR of 64-query tiles) ----------------
// NEW: 9 blocks per (b,h) instead of 16 -- each block processes two q-tiles against ONE
// staged K/V stream (region1 pairs (0,1)(2,3)(4,5)(6,dup); region2 (7,8)..(15,dup)).
// Stage + vmcnt + barriers + K/V LDS reads amortized over 2x compute; K/V refetch ~halves.
// SWAPPED layout per half: mfma(K,Q)->S^T[key][q], mfma(V^T,P)->O^T[d][q]; scalar m/l per
// lane per half; defer-max THR=8 (log2-domain). Ps rows reused across halves sequentially
// (same-wave in-order DS). All state statically indexed (rule #20).
__global__ __launch_bounds__(256, 4)
void attn_kernel(const unsigned short* __restrict__ qg,
                 const unsigned short* __restrict__ kg,
                 const unsigned short* __restrict__ vtg,
                 unsigned short* __restrict__ og) {
  __shared__ __align__(16) unsigned short Ks[2][64 * 64];
  __shared__ __align__(16) unsigned short Vts[2][64 * 64];
  __shared__ __align__(16) unsigned short Ps[64 * 64];

  const int bid = blockIdx.x;
  const int swz = (bid & 7) * 432 + (bid >> 3);   // grid 3456 = 8*432, exact XCD chunks
  const int bh = swz / 9;
  const int slot = swz - bh * 9;
  const int b = bh / H_;
  const int h = bh - b * H_;
  int kstart, ktiles, kend, qt0, qt1;
  if (slot < 4) { kstart = 1; ktiles = 7;  kend = 433;
                  qt0 = slot * 2;      qt1 = (slot < 3) ? qt0 + 1 : 6; }
  else          { kstart = 0; ktiles = 16; kend = 1009; const int s2 = slot - 4;
                  qt0 = 7 + s2 * 2;    qt1 = (s2 < 4) ? qt0 + 1 : 15; }
  const int qb0 = (qt0 < 7) ? 1 + 64 * qt0 : 433 + 64 * (qt0 - 7);
  const int qb1 = (qt1 < 7) ? 1 + 64 * qt1 : 433 + 64 * (qt1 - 7);
  const long base  = (long)bh << 10;
  const long vbase = (long)bh << 6;
  const int tid = threadIdx.x, lane = tid & 63, wv = tid >> 6;
  const int q15 = lane & 15, q7 = lane & 7, g = lane >> 4;

  // folded misc_copy: prompt segment out[b,0,h*64+d] = v[b,h,0,d] (slot 4 owns tile 7)
  if (slot == 4 && tid < 64)
    og[((long)b * N_) * 768 + h * 64 + tid] = vtg[(vbase + tid) << 10];

  s16x8 qa0[2], qa1[2];
  {
    const unsigned short* qp0 = qg + (base + qb0 + wv * 16 + q15) * 64;
    qa0[0] = *(const s16x8*)(qp0 + g * 8);
    qa0[1] = *(const s16x8*)(qp0 + 32 + g * 8);
    const unsigned short* qp1 = qg + (base + qb1 + wv * 16 + q15) * 64;
    qa1[0] = *(const s16x8*)(qp1 + g * 8);
    qa1[1] = *(const s16x8*)(qp1 + 32 + g * 8);
  }
  asm volatile("s_waitcnt vmcnt(0)" ::: "memory");

  f32x4 o0[4] = {}, o1[4] = {};
  float m0 = -1e30f, l0 = 0.f, m1 = -1e30f, l1 = 0.f;

  auto stage = [&](int bufsel, int kb0) {
#pragma unroll
    for (int it = 0; it < 2; ++it) {
      const int ldsoff = (it * 256 + wv * 64) * 16;
      const int gr = it * 256 + wv * 64 + lane;
      const int rl = gr >> 3;
      const int cs = (gr & 7) ^ (rl & 7);
      async16(kg + ((base + kb0 + rl) << 6) + cs * 8, (char*)&Ks[bufsel][0] + ldsoff);
      async16(vtg + ((vbase + rl) << 10) + kb0 + cs * 8, (char*)&Vts[bufsel][0] + ldsoff);
    }
  };

  const int prow = wv * 16 + q15;

  // one q-half: QK^T -> online softmax (defer-max) -> PV, updating (o,m,l) in place
  auto half = [&](const s16x8* qa, f32x4* o, float& mrow, float& lrow,
                  int buf, int kbase0) {
    f32x4 s4[4];
    __builtin_amdgcn_s_setprio(1);
#pragma unroll
    for (int n = 0; n < 4; ++n) {
      const int krow = n * 16 + q15;
      const int r7 = krow & 7;
      f32x4 a = {};
      a = mfma16(*(const s16x8*)&Ks[buf][krow * 64 + ((g ^ r7) << 3)],       qa[0], a);
      a = mfma16(*(const s16x8*)&Ks[buf][krow * 64 + (((4 + g) ^ r7) << 3)], qa[1], a);
      s4[n] = a;
    }
    __builtin_amdgcn_s_setprio(0);

    if (kbase0 + 64 > kend) {
#pragma unroll
      for (int n = 0; n < 4; ++n)
#pragma unroll
        for (int j = 0; j < 4; ++j)
          if (kbase0 + n * 16 + g * 4 + j >= kend) s4[n][j] = -1e30f;
    }

    float rmax = fmaxf(
        fmaxf(fmaxf(fmaxf(s4[0][0], s4[0][1]), fmaxf(s4[0][2], s4[0][3])),
              fmaxf(fmaxf(s4[1][0], s4[1][1]), fmaxf(s4[1][2], s4[1][3]))),
        fmaxf(fmaxf(fmaxf(s4[2][0], s4[2][1]), fmaxf(s4[2][2], s4[2][3])),
              fmaxf(fmaxf(s4[3][0], s4[3][1]), fmaxf(s4[3][2], s4[3][3]))));
    rmax = fmaxf(rmax, __shfl_xor(rmax, 16));
    rmax = fmaxf(rmax, __shfl_xor(rmax, 32));

    if (!__all(rmax <= mrow + 8.f)) {       // defer-max THR=8 (P <= 2^8)
      const float mnew = fmaxf(mrow, rmax);
      const float corr = exp2_fast(mrow - mnew);
      mrow = mnew;
      lrow *= corr;
#pragma unroll
      for (int f = 0; f < 4; ++f)
#pragma unroll
        for (int j = 0; j < 4; ++j) o[f][j] *= corr;
    }
    const float mnew = mrow;

    float psum = 0.f;
#pragma unroll
    for (int n = 0; n < 4; ++n) {
#pragma unroll
      for (int j = 0; j < 4; ++j) {
        s4[n][j] = exp2_fast(s4[n][j] - mnew);
        psum += s4[n][j];
      }
      uint2 pw;
      pw.x = cvt_pk_bf16(s4[n][0], s4[n][1]);
      pw.y = cvt_pk_bf16(s4[n][2], s4[n][3]);
      *(uint2*)((char*)Ps + prow * 128 + (((n * 2 + (g >> 1)) ^ q7) << 4) + (g & 1) * 8) = pw;
    }
    psum += __shfl_xor(psum, 16);
    psum += __shfl_xor(psum, 32);
    lrow += psum;

    s16x8 pa[2];
#pragma unroll
    for (int kf = 0; kf < 2; ++kf)
      pa[kf] = *(const s16x8*)((char*)Ps + prow * 128 + (((kf * 4 + g) ^ q7) << 4));
    __builtin_amdgcn_s_setprio(1);
#pragma unroll
    for (int f = 0; f < 4; ++f) {
      const int vrow = f * 16 + q15;
      const int v7 = vrow & 7;
#pragma unroll
      for (int kf = 0; kf < 2; ++kf) {
        const s16x8 vb = *(const s16x8*)&Vts[buf][vrow * 64 + (((kf * 4 + g) ^ v7) << 3)];
        o[f] = mfma16(vb, pa[kf], o[f]);
      }
    }
    __builtin_amdgcn_s_setprio(0);
  };

  stage(0, kstart);
  for (int kt = 0; kt < ktiles; ++kt) {
    const int buf = kt & 1;
    const int kbase0 = kstart + 64 * kt;
    if (kt + 1 < ktiles) {
      stage(buf ^ 1, kbase0 + 64);
      asm volatile("s_waitcnt vmcnt(4)" ::: "memory");
    } else {
      asm volatile("s_waitcnt vmcnt(0)" ::: "memory");
    }
    __builtin_amdgcn_s_barrier();

    half(qa0, o0, m0, l0, buf, kbase0);   // Ps rows reused sequentially: same-wave
    half(qa1, o1, m1, l1, buf, kbase0);   // in-order DS guarantees write-after-read

    asm volatile("s_waitcnt lgkmcnt(0)" ::: "memory");
    __builtin_amdgcn_s_barrier();
  }

  {
    const int qrow = qb0 + wv * 16 + q15;
    if (qrow < (qt0 < 7 ? 433 : 1009)) {
      const float inv = 1.0f / l0;
      unsigned short* op = og + ((long)b * N_ + qrow) * 768 + h * 64 + g * 4;
#pragma unroll
      for (int f = 0; f < 4; ++f) {
        uint2 ow;
        ow.x = cvt_pk_bf16(o0[f][0] * inv, o0[f][1] * inv);
        ow.y = cvt_pk_bf16(o0[f][2] * inv, o0[f][3] * inv);
        *(uint2*)(op + f * 16) = ow;
      }
    }
  }
  {
    const int qrow = qb1 + wv * 16 + q15;
    if (qrow < (qt1 < 7 ? 433 : 1009)) {
      const float inv = 1.0f / l1;
      unsigned short* op = og + ((long)b * N_ + qrow) * 768 + h * 64 + g * 4;
#pragma unroll
      for (int f = 0; f < 4; ++f) {
        uint2 ow;
        ow.x = cvt_pk_bf16(o1[f][0] * inv, o1[f][1] * inv);
        ow.y = cvt_pk_bf16(o1[f][2] * inv, o1[f][3] * inv);
        *(uint2*)(op + f * 16) = ow;
      }
    }
  }
}

extern "C" void kernel_launch(void* const* d_in, const int* in_sizes, int n_in,
                              void* d_out, int out_size, void* d_ws, size_t ws_size,
                              hipStream_t stream) {
  const float* x      = (const float*)d_in[0];
  const float* W_qkv  = (const float*)d_in[1];
  const float* b_qkv  = (const float*)d_in[2];
  const float* W_proj = (const float*)d_in[3];
  const float* b_proj = (const float*)d_in[4];
  float* out = (float*)d_out;

  unsigned short* ws = (unsigned short*)d_ws;
  unsigned short* wqkvT  = ws;                                  // [2304][768] bf16
  unsigned short* wprojT = wqkvT + (long)2304 * 768;            // [768][768] bf16
  unsigned short* qb = wprojT + (long)768 * 768;                // [B][H][1024][64] bf16
  const long kvsz = (long)B_ * H_ * NKV_ * D_;
  unsigned short* kb = qb + kvsz;                               // [B][H][1024][64] bf16
  unsigned short* vb = kb + kvsz;                               // V^T: [B][H][64][1024] bf16
  unsigned short* xb = vb + kvsz;                               // [MPAD][768] bf16
  unsigned short* attnout = xb;  // aliased: xb dead after QKV GEMM (stream-ordered)

  prep<<<14160, 256, 0, stream>>>(x, xb, W_qkv, wqkvT, W_proj, wprojT, kb, vb);
  gemm_bt<0><<<MT_ * 18, 256, 0, stream>>>(xb, wqkvT, b_qkv, qb, kb, vb, nullptr);
  attn_kernel<<<B_ * H_ * 9, 256, 0, stream>>>(qb, kb, vb, attnout);
  gemm_bt<1><<<MT_ * 6, 256, 0, stream>>>(attnout, wprojT, b_proj, nullptr, nullptr, nullptr, out);
}